// Round 2
// baseline (1016.297 us; speedup 1.0000x reference)
//
#include <hip/hip_runtime.h>
#include <hip/hip_bf16.h>
#include <math.h>

// Problem constants (fixed by the reference file)
#define NPTS 262144
#define NP   128
#define DD   64
#define NWORDS (NPTS / 64)   // 4096 u64 ballot words per plane

// AS(4) scalar pointers for small uniform reads (planes/BN). R7 lesson: use
// POD ext_vector for AS(4) vectors (HIP float4 ctors break the host pass).
#define AS4 __attribute__((address_space(4)))
typedef float evf4 __attribute__((ext_vector_type(4)));
typedef AS4 const float* csf;
typedef AS4 const evf4*  csf4;
#define TO_CSF(p)  ((csf)(unsigned long long)(const void*)(p))
#define TO_CSF4(p) ((csf4)(unsigned long long)(const void*)(p))

// ---------------------------------------------------------------------------
// Prep: pack plane params [P][12] (normal.xyz+offs | min.xyz | max.xyz),
// transpose w2 -> w2T[j][k], zero out_feats for the atomic-max pool.
// ---------------------------------------------------------------------------
__global__ __launch_bounds__(256) void prep_kernel(
    const float* __restrict__ plane_center, const float* __restrict__ plane_normal,
    const float* __restrict__ pmin, const float* __restrict__ pmax,
    const float* __restrict__ w2,
    float* __restrict__ packed, float* __restrict__ w2T,
    float* __restrict__ out_feats)
{
    const int t = threadIdx.x;
    out_feats[blockIdx.x * 256 + t] = 0.0f;          // grid = 64 blocks
    if (blockIdx.x == 0 && t < NP) {
        float n0 = plane_normal[t*3+0], n1 = plane_normal[t*3+1], n2 = plane_normal[t*3+2];
        float c0 = plane_center[t*3+0], c1 = plane_center[t*3+1], c2 = plane_center[t*3+2];
        float off = (c0*n0 + c1*n1) + c2*n2;          // matches jnp.sum order
        float4* pp = reinterpret_cast<float4*>(packed) + t * 3;
        pp[0] = make_float4(n0, n1, n2, off);
        pp[1] = make_float4(pmin[t*3+0], pmin[t*3+1], pmin[t*3+2], 0.0f);
        pp[2] = make_float4(pmax[t*3+0], pmax[t*3+1], pmax[t*3+2], 0.0f);
    }
    if (blockIdx.x == 1) {
#pragma unroll
        for (int u = 0; u < 16; ++u) {
            const int e = u * 256 + t;               // e = j*64 + k
            const int j = e >> 6, k = e & 63;
            w2T[e] = w2[k * DD + j];
        }
    }
}

// ---------------------------------------------------------------------------
// Fused per-point kernel, round-11: TWO POINTS PER THREAD + PINNED OCCUPANCY.
// R10 post-mortem: with __launch_bounds__(256,2) the allocator still chose
// 128 VGPR (4 waves/EU target) and spilled the 128 live accumulators ->
// +316MB FETCH / +440MB WRITE of scratch traffic, fused 429us. The grid is
// 512 blocks = 2 blocks/CU = 8 waves/CU, so 4 waves/EU was unreachable
// anyway. Fix: amdgpu_waves_per_eu(2,2) pins the budget at 256 VGPR, which
// fits acc0[64]+acc1[64]+working (~180) with zero spill.
// Rationale for 2-pt (unchanged from R10): each wave-broadcast ds_read_b128
// costs ~4 CU-cycles of LDS return BW but its 4 FMAs only 2 CU-cycles of
// VALU issue -> 1-pt fc was ~2x LDS-bound; feeding 8 FMAs per read
// rebalances. FMA order per point is bit-identical -> absmax 2.98e-8.
// ---------------------------------------------------------------------------
#define FMA4(ACC, FS, W, J) \
    ACC[4*(J)+0] = fmaf((FS), (W).x, ACC[4*(J)+0]); \
    ACC[4*(J)+1] = fmaf((FS), (W).y, ACC[4*(J)+1]); \
    ACC[4*(J)+2] = fmaf((FS), (W).z, ACC[4*(J)+2]); \
    ACC[4*(J)+3] = fmaf((FS), (W).w, ACC[4*(J)+3]);

__global__ __attribute__((amdgpu_flat_work_group_size(256, 256)))
__attribute__((amdgpu_waves_per_eu(2, 2))) void fused_kernel(
    const float* __restrict__ feature, const float* __restrict__ feature_geo,
    const float* __restrict__ xyz, const float* __restrict__ centers,
    const float* __restrict__ packed,
    const float* __restrict__ w1, const float* __restrict__ b1,
    const float* __restrict__ g1, const float* __restrict__ be1,
    const float* __restrict__ m1, const float* __restrict__ v1,
    const float* __restrict__ w2T, const float* __restrict__ b2,
    const float* __restrict__ g2, const float* __restrict__ be2,
    const float* __restrict__ m2, const float* __restrict__ v2,
    const float* __restrict__ w3, const float* __restrict__ b3,
    float* __restrict__ h2_out,
    float* __restrict__ out_sm, float* __restrict__ out_mask,
    float* __restrict__ out_on, float* __restrict__ out_off,
    unsigned long long* __restrict__ hitOn, unsigned long long* __restrict__ hitOff)
{
    __shared__ float sw1[128 * DD];   // 32 KB, row-major [k][j] like w1
    __shared__ float sw2[DD * DD];    // 16 KB, w2T layout [j][k]
    const int t = threadIdx.x;
    const int n0 = blockIdx.x * 512 + t;
    const int n1 = n0 + 256;
    const int lane = t & 63;
    const int word0 = n0 >> 6;        // wave-uniform; point1 word = word0 + 4

    // stage weights (coalesced float4; 12 per thread)
    {
        const float4* s1 = reinterpret_cast<const float4*>(w1);
        const float4* s2 = reinterpret_cast<const float4*>(w2T);
        float4* d1 = reinterpret_cast<float4*>(sw1);
        float4* d2 = reinterpret_cast<float4*>(sw2);
#pragma unroll
        for (int k = 0; k < 8; ++k) d1[t + k * 256] = s1[t + k * 256];
#pragma unroll
        for (int k = 0; k < 4; ++k) d2[t + k * 256] = s2[t + k * 256];
    }

    // cloud coords for both points (issue early; used in Phase C)
    const csf cc = TO_CSF(centers);
    const float ca0 = xyz[n0*3+0] + cc[0];
    const float ca1 = xyz[n0*3+1] + cc[1];
    const float ca2 = xyz[n0*3+2] + cc[2];
    const float cb0 = xyz[n1*3+0] + cc[0];
    const float cb1 = xyz[n1*3+1] + cc[1];
    const float cb2 = xyz[n1*3+2] + cc[2];

    __syncthreads();

    float acc0[DD], acc1[DD];
#pragma unroll
    for (int j = 0; j < DD; ++j) { acc0[j] = 0.0f; acc1[j] = 0.0f; }

    // ---- Phase A: fc1 from LDS (q rolled, j-blocks as 16x b128) ----
    const float4* fA0 = reinterpret_cast<const float4*>(feature) + (size_t)n0 * 16;
    const float4* fA1 = reinterpret_cast<const float4*>(feature) + (size_t)n1 * 16;
    const float4* fB0 = reinterpret_cast<const float4*>(feature_geo) + (size_t)n0 * 16;
    const float4* fB1 = reinterpret_cast<const float4*>(feature_geo) + (size_t)n1 * 16;
#pragma unroll 1
    for (int q = 0; q < 16; ++q) {
        const float4 f0 = fA0[q];
        const float4 f1 = fA1[q];
        const evf4* wr = reinterpret_cast<const evf4*>(sw1 + q * 4 * DD);
#pragma unroll
        for (int j4 = 0; j4 < 16; ++j4) { const evf4 w = wr[j4];
            FMA4(acc0, f0.x, w, j4) FMA4(acc1, f1.x, w, j4) }
#pragma unroll
        for (int j4 = 0; j4 < 16; ++j4) { const evf4 w = wr[16 + j4];
            FMA4(acc0, f0.y, w, j4) FMA4(acc1, f1.y, w, j4) }
#pragma unroll
        for (int j4 = 0; j4 < 16; ++j4) { const evf4 w = wr[32 + j4];
            FMA4(acc0, f0.z, w, j4) FMA4(acc1, f1.z, w, j4) }
#pragma unroll
        for (int j4 = 0; j4 < 16; ++j4) { const evf4 w = wr[48 + j4];
            FMA4(acc0, f0.w, w, j4) FMA4(acc1, f1.w, w, j4) }
    }
#pragma unroll 1
    for (int q = 0; q < 16; ++q) {
        const float4 f0 = fB0[q];
        const float4 f1 = fB1[q];
        const evf4* wr = reinterpret_cast<const evf4*>(sw1 + (DD + q * 4) * DD);
#pragma unroll
        for (int j4 = 0; j4 < 16; ++j4) { const evf4 w = wr[j4];
            FMA4(acc0, f0.x, w, j4) FMA4(acc1, f1.x, w, j4) }
#pragma unroll
        for (int j4 = 0; j4 < 16; ++j4) { const evf4 w = wr[16 + j4];
            FMA4(acc0, f0.y, w, j4) FMA4(acc1, f1.y, w, j4) }
#pragma unroll
        for (int j4 = 0; j4 < 16; ++j4) { const evf4 w = wr[32 + j4];
            FMA4(acc0, f0.z, w, j4) FMA4(acc1, f1.z, w, j4) }
#pragma unroll
        for (int j4 = 0; j4 < 16; ++j4) { const evf4 w = wr[48 + j4];
            FMA4(acc0, f0.w, w, j4) FMA4(acc1, f1.w, w, j4) }
    }
    // BN1 + ReLU in place (exact same per-point arithmetic/order; the
    // scale sc is wave-uniform and shared between the two points)
    {
        const csf g1c = TO_CSF(g1), v1c = TO_CSF(v1), b1c = TO_CSF(b1),
                  m1c = TO_CSF(m1), be1c = TO_CSF(be1);
#pragma unroll
        for (int j = 0; j < DD; ++j) {
            float sc = g1c[j] * (1.0f / sqrtf(v1c[j] + 1e-5f));
            float h0 = fmaf(acc0[j] + b1c[j] - m1c[j], sc, be1c[j]);
            float h1 = fmaf(acc1[j] + b1c[j] - m1c[j], sc, be1c[j]);
            acc0[j] = fmaxf(h0, 0.0f);
            acc1[j] = fmaxf(h1, 0.0f);
        }
    }

    // ---- Phase B: fc2 from LDS w2T rows + BN2 + ReLU + fc3 + h2 store ----
    const csf g2c = TO_CSF(g2), v2c = TO_CSF(v2), b2c = TO_CSF(b2),
              m2c = TO_CSF(m2), be2c = TO_CSF(be2), w3c = TO_CSF(w3);
    float s0 = 0.0f, s1 = 0.0f;
    float4* o0 = reinterpret_cast<float4*>(h2_out) + (size_t)n0 * 16;
    float4* o1 = reinterpret_cast<float4*>(h2_out) + (size_t)n1 * 16;
#pragma unroll 1
    for (int jq = 0; jq < 16; ++jq) {
        const evf4* r0 = reinterpret_cast<const evf4*>(sw2 + (4*jq + 0) * DD);
        const evf4* r1 = reinterpret_cast<const evf4*>(sw2 + (4*jq + 1) * DD);
        const evf4* r2 = reinterpret_cast<const evf4*>(sw2 + (4*jq + 2) * DD);
        const evf4* r3 = reinterpret_cast<const evf4*>(sw2 + (4*jq + 3) * DD);
        float a00 = 0.0f, a01 = 0.0f, a02 = 0.0f, a03 = 0.0f;
        float a10 = 0.0f, a11 = 0.0f, a12 = 0.0f, a13 = 0.0f;
#pragma unroll
        for (int k4 = 0; k4 < 16; ++k4) {
            const evf4 w0 = r0[k4], w1v = r1[k4], w2v = r2[k4], w3v = r3[k4];
            {
                const float h0 = acc0[4*k4+0], h1v = acc0[4*k4+1],
                            h2v = acc0[4*k4+2], h3v = acc0[4*k4+3];
                a00 = fmaf(h0, w0.x, a00); a00 = fmaf(h1v, w0.y, a00);
                a00 = fmaf(h2v, w0.z, a00); a00 = fmaf(h3v, w0.w, a00);
                a01 = fmaf(h0, w1v.x, a01); a01 = fmaf(h1v, w1v.y, a01);
                a01 = fmaf(h2v, w1v.z, a01); a01 = fmaf(h3v, w1v.w, a01);
                a02 = fmaf(h0, w2v.x, a02); a02 = fmaf(h1v, w2v.y, a02);
                a02 = fmaf(h2v, w2v.z, a02); a02 = fmaf(h3v, w2v.w, a02);
                a03 = fmaf(h0, w3v.x, a03); a03 = fmaf(h1v, w3v.y, a03);
                a03 = fmaf(h2v, w3v.z, a03); a03 = fmaf(h3v, w3v.w, a03);
            }
            {
                const float h0 = acc1[4*k4+0], h1v = acc1[4*k4+1],
                            h2v = acc1[4*k4+2], h3v = acc1[4*k4+3];
                a10 = fmaf(h0, w0.x, a10); a10 = fmaf(h1v, w0.y, a10);
                a10 = fmaf(h2v, w0.z, a10); a10 = fmaf(h3v, w0.w, a10);
                a11 = fmaf(h0, w1v.x, a11); a11 = fmaf(h1v, w1v.y, a11);
                a11 = fmaf(h2v, w1v.z, a11); a11 = fmaf(h3v, w1v.w, a11);
                a12 = fmaf(h0, w2v.x, a12); a12 = fmaf(h1v, w2v.y, a12);
                a12 = fmaf(h2v, w2v.z, a12); a12 = fmaf(h3v, w2v.w, a12);
                a13 = fmaf(h0, w3v.x, a13); a13 = fmaf(h1v, w3v.y, a13);
                a13 = fmaf(h2v, w3v.z, a13); a13 = fmaf(h3v, w3v.w, a13);
            }
        }
        float hv0[4] = {a00, a01, a02, a03};
        float hv1[4] = {a10, a11, a12, a13};
#pragma unroll
        for (int u = 0; u < 4; ++u) {
            const int jj = 4*jq + u;
            float sc = g2c[jj] * (1.0f / sqrtf(v2c[jj] + 1e-5f));
            float h0 = fmaf(hv0[u] + b2c[jj] - m2c[jj], sc, be2c[jj]);
            float h1 = fmaf(hv1[u] + b2c[jj] - m2c[jj], sc, be2c[jj]);
            h0 = fmaxf(h0, 0.0f);
            h1 = fmaxf(h1, 0.0f);
            hv0[u] = h0; hv1[u] = h1;
            s0 = fmaf(h0, w3c[jj], s0);
            s1 = fmaf(h1, w3c[jj], s1);
        }
        o0[jq] = make_float4(hv0[0], hv0[1], hv0[2], hv0[3]);
        o1[jq] = make_float4(hv1[0], hv1[1], hv1[2], hv1[3]);
    }
    const float bb3 = TO_CSF(b3)[0];
    const float score0 = fmaxf(s0 + bb3, 0.0f);
    const float score1 = fmaxf(s1 + bb3, 0.0f);

    // sigmoid(score) > 0.5 via XLA-style logistic expansion (score >= 0)
    const bool on0 = (0.5f + 0.5f * tanhf(0.5f * score0)) > 0.5f;
    const bool on1 = (0.5f + 0.5f * tanhf(0.5f * score1)) > 0.5f;

    // ---- Phase C: geometry + 4x2 output stores + 2x2 ballots per plane ----
    const csf4 pp = TO_CSF4(packed);
#pragma unroll 1
    for (int p = 0; p < NP; ++p) {
        const evf4 nrm = pp[p*3+0];
        const evf4 mn  = pp[p*3+1];
        const evf4 mx  = pp[p*3+2];
        // point 0
        float dA = fabsf(fmaf(ca2, nrm.z, fmaf(ca1, nrm.y, ca0 * nrm.x)) - nrm.w);
        bool okA0 = (mx.x == 0.0f) | ((ca0 >= mn.x) & (ca0 < mx.x));
        bool okA1 = (mx.y == 0.0f) | ((ca1 >= mn.y) & (ca1 < mx.y));
        bool okA2 = (mx.z == 0.0f) | ((ca2 >= mn.z) & (ca2 < mx.z));
        bool mkA  = okA0 & okA1 & okA2 & (dA < 0.1f);
        // point 1
        float dB = fabsf(fmaf(cb2, nrm.z, fmaf(cb1, nrm.y, cb0 * nrm.x)) - nrm.w);
        bool okB0 = (mx.x == 0.0f) | ((cb0 >= mn.x) & (cb0 < mx.x));
        bool okB1 = (mx.y == 0.0f) | ((cb1 >= mn.y) & (cb1 < mx.y));
        bool okB2 = (mx.z == 0.0f) | ((cb2 >= mn.z) & (cb2 < mx.z));
        bool mkB  = okB0 & okB1 & okB2 & (dB < 0.1f);

        const size_t idxA = (size_t)p * NPTS + n0;   // idxB = idxA + 256
        const bool monA  = mkA & on0;
        const bool moffA = mkA & (!on0);
        const bool monB  = mkB & on1;
        const bool moffB = mkB & (!on1);
        out_mask[idxA]       = mkA ? 1.0f : 0.0f;
        out_mask[idxA + 256] = mkB ? 1.0f : 0.0f;
        out_sm[idxA]         = mkA ? score0 : 0.0f;
        out_sm[idxA + 256]   = mkB ? score1 : 0.0f;
        out_on[idxA]         = monA ? 1.0f : 0.0f;
        out_on[idxA + 256]   = monB ? 1.0f : 0.0f;
        out_off[idxA]        = moffA ? 1.0f : 0.0f;
        out_off[idxA + 256]  = moffB ? 1.0f : 0.0f;
        unsigned long long bOnA  = __ballot(monA);
        unsigned long long bOffA = __ballot(moffA);
        unsigned long long bOnB  = __ballot(monB);
        unsigned long long bOffB = __ballot(moffB);
        if (lane == 0) {
            hitOn [(size_t)p * NWORDS + word0]     = bOnA;
            hitOn [(size_t)p * NWORDS + word0 + 4] = bOnB;
            hitOff[(size_t)p * NWORDS + word0]     = bOffA;
            hitOff[(size_t)p * NWORDS + word0 + 4] = bOffB;
        }
    }
}

// ---------------------------------------------------------------------------
// Pool: masked max of h2 per plane, register-accumulated per block, then
// atomicMax(int) into out_feats (non-negative IEEE floats compare as signed
// ints; h2 >= 0; zero-init by prep -> exact where(any,max,0) semantics).
// Wave w owns planes [32w,32w+32); lane = dim; hit loop is wave-uniform.
// tile[n*64+lane]: 2-way bank alias = free (m136).
// ---------------------------------------------------------------------------
__global__ __launch_bounds__(256) void pool_kernel(
    const float* __restrict__ h2,
    const unsigned long long* __restrict__ hitOn,
    const unsigned long long* __restrict__ hitOff,
    int* __restrict__ out_feats_i)
{
    __shared__ float tile[128 * DD];                 // 32 KB
    __shared__ unsigned long long bm[2][NP][2];      // 4 KB
    const int t = threadIdx.x;
    const int lane = t & 63;
    const int wv = t >> 6;

    float accOn[32], accOff[32];
#pragma unroll
    for (int i = 0; i < 32; ++i) { accOn[i] = 0.0f; accOff[i] = 0.0f; }

    for (int cc = 0; cc < 4; ++cc) {
        const int chunk = blockIdx.x * 4 + cc;       // 0..2047
        const int base  = chunk * 128;
        const float4* src = reinterpret_cast<const float4*>(h2 + (size_t)base * DD);
        float4* dst = reinterpret_cast<float4*>(tile);
#pragma unroll
        for (int q = 0; q < 8; ++q) dst[t + q * 256] = src[t + q * 256];
        {
            const int p = t & 127;
            const int half = t >> 7;
            const unsigned long long* hsrc = half ? hitOff : hitOn;
            const int w0 = chunk * 2;
            bm[half][p][0] = hsrc[(size_t)p * NWORDS + w0 + 0];
            bm[half][p][1] = hsrc[(size_t)p * NWORDS + w0 + 1];
        }
        __syncthreads();

#pragma unroll
        for (int i = 0; i < 32; ++i) {
            const int p = wv * 32 + i;
            unsigned long long m;
            m = bm[0][p][0];
            while (m) { int nn = __builtin_ctzll(m); m &= m - 1;
                        accOn[i]  = fmaxf(accOn[i],  tile[nn * DD + lane]); }
            m = bm[0][p][1];
            while (m) { int nn = __builtin_ctzll(m); m &= m - 1;
                        accOn[i]  = fmaxf(accOn[i],  tile[(64 + nn) * DD + lane]); }
            m = bm[1][p][0];
            while (m) { int nn = __builtin_ctzll(m); m &= m - 1;
                        accOff[i] = fmaxf(accOff[i], tile[nn * DD + lane]); }
            m = bm[1][p][1];
            while (m) { int nn = __builtin_ctzll(m); m &= m - 1;
                        accOff[i] = fmaxf(accOff[i], tile[(64 + nn) * DD + lane]); }
        }
        __syncthreads();
    }
#pragma unroll
    for (int i = 0; i < 32; ++i) {
        const int p = wv * 32 + i;
        if (accOn[i]  != 0.0f) atomicMax(&out_feats_i[p * DD + lane],            __float_as_int(accOn[i]));
        if (accOff[i] != 0.0f) atomicMax(&out_feats_i[NP * DD + p * DD + lane],  __float_as_int(accOff[i]));
    }
}

extern "C" void kernel_launch(void* const* d_in, const int* in_sizes, int n_in,
                              void* d_out, int out_size, void* d_ws, size_t ws_size,
                              hipStream_t stream) {
    const float* feature      = (const float*)d_in[0];
    const float* feature_geo  = (const float*)d_in[1];
    const float* xyz          = (const float*)d_in[2];
    const float* centers      = (const float*)d_in[3];
    const float* plane_center = (const float*)d_in[4];
    const float* plane_normal = (const float*)d_in[5];
    const float* pmin         = (const float*)d_in[6];
    const float* pmax         = (const float*)d_in[7];
    const float* w1 = (const float*)d_in[8];
    const float* b1 = (const float*)d_in[9];
    const float* g1 = (const float*)d_in[10];
    const float* be1 = (const float*)d_in[11];
    const float* m1 = (const float*)d_in[12];
    const float* v1 = (const float*)d_in[13];
    const float* w2 = (const float*)d_in[14];
    const float* b2 = (const float*)d_in[15];
    const float* g2 = (const float*)d_in[16];
    const float* be2 = (const float*)d_in[17];
    const float* m2 = (const float*)d_in[18];
    const float* v2 = (const float*)d_in[19];
    const float* w3 = (const float*)d_in[20];
    const float* b3 = (const float*)d_in[21];

    float* out = (float*)d_out;
    const size_t PN = (size_t)NP * NPTS;
    float* out_sm    = out;
    float* out_mask  = out + PN;
    float* out_on    = out + 2 * PN;
    float* out_off   = out + 3 * PN;
    float* out_feats = out + 4 * PN;

    // workspace carve (~73 MB)
    float* h2     = (float*)d_ws;                                // N*64 f32 (64 MB)
    unsigned long long* hitOn  = (unsigned long long*)(h2 + (size_t)NPTS * DD);
    unsigned long long* hitOff = hitOn + (size_t)NP * NWORDS;
    float* packed = (float*)(hitOff + (size_t)NP * NWORDS);      // P*12 f32
    float* w2T    = packed + NP * 12;                            // 64*64 f32

    prep_kernel<<<64, 256, 0, stream>>>(
        plane_center, plane_normal, pmin, pmax, w2, packed, w2T, out_feats);
    fused_kernel<<<NPTS / 512, 256, 0, stream>>>(
        feature, feature_geo, xyz, centers, packed,
        w1, b1, g1, be1, m1, v1, w2T, b2, g2, be2, m2, v2, w3, b3,
        h2, out_sm, out_mask, out_on, out_off, hitOn, hitOff);
    pool_kernel<<<512, 256, 0, stream>>>(h2, hitOn, hitOff, (int*)out_feats);
}

// Round 3
// 909.507 us; speedup vs baseline: 1.1174x; 1.1174x over previous
//
#include <hip/hip_runtime.h>
#include <hip/hip_bf16.h>
#include <math.h>

// Problem constants (fixed by the reference file)
#define NPTS 262144
#define NP   128
#define DD   64
#define NWORDS (NPTS / 64)   // 4096 u64 ballot words per plane

// AS(4) scalar pointers for small uniform reads (planes/BN). R7 lesson: use
// POD ext_vector for AS(4) vectors (HIP float4 ctors break the host pass).
#define AS4 __attribute__((address_space(4)))
typedef float evf4 __attribute__((ext_vector_type(4)));
typedef AS4 const float* csf;
typedef AS4 const evf4*  csf4;
#define TO_CSF(p)  ((csf)(unsigned long long)(const void*)(p))
#define TO_CSF4(p) ((csf4)(unsigned long long)(const void*)(p))

// ---------------------------------------------------------------------------
// Prep: pack plane params [P][12] (normal.xyz+offs | min.xyz | max.xyz),
// transpose w2 -> w2T[j][k], zero out_feats for the atomic-max pool.
// ---------------------------------------------------------------------------
__global__ __launch_bounds__(256) void prep_kernel(
    const float* __restrict__ plane_center, const float* __restrict__ plane_normal,
    const float* __restrict__ pmin, const float* __restrict__ pmax,
    const float* __restrict__ w2,
    float* __restrict__ packed, float* __restrict__ w2T,
    float* __restrict__ out_feats)
{
    const int t = threadIdx.x;
    out_feats[blockIdx.x * 256 + t] = 0.0f;          // grid = 64 blocks
    if (blockIdx.x == 0 && t < NP) {
        float n0 = plane_normal[t*3+0], n1 = plane_normal[t*3+1], n2 = plane_normal[t*3+2];
        float c0 = plane_center[t*3+0], c1 = plane_center[t*3+1], c2 = plane_center[t*3+2];
        float off = (c0*n0 + c1*n1) + c2*n2;          // matches jnp.sum order
        float4* pp = reinterpret_cast<float4*>(packed) + t * 3;
        pp[0] = make_float4(n0, n1, n2, off);
        pp[1] = make_float4(pmin[t*3+0], pmin[t*3+1], pmin[t*3+2], 0.0f);
        pp[2] = make_float4(pmax[t*3+0], pmax[t*3+1], pmax[t*3+2], 0.0f);
    }
    if (blockIdx.x == 1) {
#pragma unroll
        for (int u = 0; u < 16; ++u) {
            const int e = u * 256 + t;               // e = j*64 + k
            const int j = e >> 6, k = e & 63;
            w2T[e] = w2[k * DD + j];
        }
    }
}

// ---------------------------------------------------------------------------
// Fused per-point kernel, round-12: DIM-SPLIT Phase A.
// R10/R11 post-mortem: 2-pt-all-dims needs 128 live accs; the allocator
// refuses >128 VGPR (launch_bounds(256,2) AND waves_per_eu(2,2) both left
// VGPR_Count=128) and spilled ~1GB of scratch traffic. Same amortization,
// quarter the footprint: lane pairs (lane, lane^32) co-own points
// (ptA, ptB); in Phase A lo lanes compute dims 0-31 for BOTH points, hi
// lanes dims 32-63. Each weight ds_read_b128 feeds 8 FMAs (2x R9) and
// Phase A's LDS instr count halves (2048->1024/wave, 2-addr reads = free
// 2-way alias per m136). Live accs = 2x32 = 64 regs -> fits the 128
// budget, no spill. Feature loads: lanes p and p+32 hit the same address
// -> coalesced merge, no extra HBM. After BN1 a 32-step shfl_xor(32)
// exchange gives each thread full h1[64] for point n = bid*256+t; Phase B,
// score chain, Phase C, stores, ballots are verbatim R9 -> bit-identical
// output (absmax 2.98e-8). BN1 params staged in LDS (jj is lane-divergent,
// AS4 scalar loads don't apply). LDS 49.5KB -> still 3 blocks/CU.
// ---------------------------------------------------------------------------
#define FMA4(ACC, FS, W, J) \
    ACC[4*(J)+0] = fmaf((FS), (W).x, ACC[4*(J)+0]); \
    ACC[4*(J)+1] = fmaf((FS), (W).y, ACC[4*(J)+1]); \
    ACC[4*(J)+2] = fmaf((FS), (W).z, ACC[4*(J)+2]); \
    ACC[4*(J)+3] = fmaf((FS), (W).w, ACC[4*(J)+3]);

__global__ __launch_bounds__(256) void fused_kernel(
    const float* __restrict__ feature, const float* __restrict__ feature_geo,
    const float* __restrict__ xyz, const float* __restrict__ centers,
    const float* __restrict__ packed,
    const float* __restrict__ w1, const float* __restrict__ b1,
    const float* __restrict__ g1, const float* __restrict__ be1,
    const float* __restrict__ m1, const float* __restrict__ v1,
    const float* __restrict__ w2T, const float* __restrict__ b2,
    const float* __restrict__ g2, const float* __restrict__ be2,
    const float* __restrict__ m2, const float* __restrict__ v2,
    const float* __restrict__ w3, const float* __restrict__ b3,
    float* __restrict__ h2_out,
    float* __restrict__ out_sm, float* __restrict__ out_mask,
    float* __restrict__ out_on, float* __restrict__ out_off,
    unsigned long long* __restrict__ hitOn, unsigned long long* __restrict__ hitOff)
{
    __shared__ float sw1[128 * DD];   // 32 KB, row-major [k][j] like w1
    __shared__ float sw2[DD * DD];    // 16 KB, w2T layout [j][k]
    __shared__ float sbn1[5 * DD];    // 1.25 KB: b1|m1|g1|v1|be1
    const int t = threadIdx.x;
    const int n = blockIdx.x * 256 + t;   // point owned after the exchange
    const int lane = t & 63;
    const int word = n >> 6;
    const int p = lane & 31;
    const int half = lane >> 5;           // 0: dims 0-31, 1: dims 32-63
    const int dimoff = half * 32;
    const int wavebase = blockIdx.x * 256 + (t >> 6) * 64;
    const int ptA = wavebase + p;         // lo-thread's final point
    const int ptB = wavebase + 32 + p;    // hi-thread's final point

    // stage weights (coalesced float4; 12 per thread) + BN1 params
    {
        const float4* s1 = reinterpret_cast<const float4*>(w1);
        const float4* s2 = reinterpret_cast<const float4*>(w2T);
        float4* d1 = reinterpret_cast<float4*>(sw1);
        float4* d2 = reinterpret_cast<float4*>(sw2);
#pragma unroll
        for (int k = 0; k < 8; ++k) d1[t + k * 256] = s1[t + k * 256];
#pragma unroll
        for (int k = 0; k < 4; ++k) d2[t + k * 256] = s2[t + k * 256];
        if (t < DD) {
            sbn1[t]          = b1[t];
            sbn1[DD + t]     = m1[t];
            sbn1[2*DD + t]   = g1[t];
            sbn1[3*DD + t]   = v1[t];
            sbn1[4*DD + t]   = be1[t];
        }
    }

    // cloud coords for point n (issue early; used in Phase C)
    const csf cc = TO_CSF(centers);
    const float c0 = xyz[n*3+0] + cc[0];
    const float c1 = xyz[n*3+1] + cc[1];
    const float c2 = xyz[n*3+2] + cc[2];

    __syncthreads();

    // ---- Phase A: fc1, dim-split: a0 = ptA dims [dimoff,dimoff+32),
    //      a1 = ptB same dims. 8 FMAs per ds_read_b128. ----
    float a0[32], a1[32];
#pragma unroll
    for (int j = 0; j < 32; ++j) { a0[j] = 0.0f; a1[j] = 0.0f; }

    const float4* fA0 = reinterpret_cast<const float4*>(feature) + (size_t)ptA * 16;
    const float4* fA1 = reinterpret_cast<const float4*>(feature) + (size_t)ptB * 16;
    const float4* fB0 = reinterpret_cast<const float4*>(feature_geo) + (size_t)ptA * 16;
    const float4* fB1 = reinterpret_cast<const float4*>(feature_geo) + (size_t)ptB * 16;
#pragma unroll 1
    for (int q = 0; q < 16; ++q) {
        const float4 f0 = fA0[q];
        const float4 f1 = fA1[q];
        const evf4* wr = reinterpret_cast<const evf4*>(sw1 + q * 4 * DD + dimoff);
#pragma unroll
        for (int j4 = 0; j4 < 8; ++j4) { const evf4 w = wr[j4];
            FMA4(a0, f0.x, w, j4) FMA4(a1, f1.x, w, j4) }
#pragma unroll
        for (int j4 = 0; j4 < 8; ++j4) { const evf4 w = wr[16 + j4];
            FMA4(a0, f0.y, w, j4) FMA4(a1, f1.y, w, j4) }
#pragma unroll
        for (int j4 = 0; j4 < 8; ++j4) { const evf4 w = wr[32 + j4];
            FMA4(a0, f0.z, w, j4) FMA4(a1, f1.z, w, j4) }
#pragma unroll
        for (int j4 = 0; j4 < 8; ++j4) { const evf4 w = wr[48 + j4];
            FMA4(a0, f0.w, w, j4) FMA4(a1, f1.w, w, j4) }
    }
#pragma unroll 1
    for (int q = 0; q < 16; ++q) {
        const float4 f0 = fB0[q];
        const float4 f1 = fB1[q];
        const evf4* wr = reinterpret_cast<const evf4*>(sw1 + (DD + q * 4) * DD + dimoff);
#pragma unroll
        for (int j4 = 0; j4 < 8; ++j4) { const evf4 w = wr[j4];
            FMA4(a0, f0.x, w, j4) FMA4(a1, f1.x, w, j4) }
#pragma unroll
        for (int j4 = 0; j4 < 8; ++j4) { const evf4 w = wr[16 + j4];
            FMA4(a0, f0.y, w, j4) FMA4(a1, f1.y, w, j4) }
#pragma unroll
        for (int j4 = 0; j4 < 8; ++j4) { const evf4 w = wr[32 + j4];
            FMA4(a0, f0.z, w, j4) FMA4(a1, f1.z, w, j4) }
#pragma unroll
        for (int j4 = 0; j4 < 8; ++j4) { const evf4 w = wr[48 + j4];
            FMA4(a0, f0.w, w, j4) FMA4(a1, f1.w, w, j4) }
    }
    // BN1 + ReLU on the owned dim-half (same arithmetic/order per dim as R9;
    // params from LDS copies -> identical float values)
#pragma unroll
    for (int j = 0; j < 32; ++j) {
        const int jj = dimoff + j;
        float sc = sbn1[2*DD + jj] * (1.0f / sqrtf(sbn1[3*DD + jj] + 1e-5f));
        float h0 = fmaf(a0[j] + sbn1[jj] - sbn1[DD + jj], sc, sbn1[4*DD + jj]);
        float h1 = fmaf(a1[j] + sbn1[jj] - sbn1[DD + jj], sc, sbn1[4*DD + jj]);
        a0[j] = fmaxf(h0, 0.0f);
        a1[j] = fmaxf(h1, 0.0f);
    }

    // ---- Exchange: assemble full h1[64] for point n (= ptA on lo lanes,
    //      ptB on hi lanes). lo sends its ptB dims, hi sends its ptA dims. ----
    float acc[DD];
#pragma unroll
    for (int i = 0; i < 32; ++i) {
        const float send = half ? a0[i] : a1[i];
        const float recv = __shfl_xor(send, 32, 64);
        const float own  = half ? a1[i] : a0[i];
        acc[dimoff + i] = own;                 // own half
        acc[(half ? 0 : 32) + i] = recv;       // partner half
    }

    // ---- Phase B: fc2 from LDS w2T rows + BN2 + ReLU + fc3 + h2 store ----
    // (verbatim R9: 1 point/thread, full dims, exact fc2/fc3 chain order)
    const csf g2c = TO_CSF(g2), v2c = TO_CSF(v2), b2c = TO_CSF(b2),
              m2c = TO_CSF(m2), be2c = TO_CSF(be2), w3c = TO_CSF(w3);
    float s = 0.0f;
    float4* o = reinterpret_cast<float4*>(h2_out) + (size_t)n * 16;
#pragma unroll 1
    for (int jq = 0; jq < 16; ++jq) {
        const evf4* r0 = reinterpret_cast<const evf4*>(sw2 + (4*jq + 0) * DD);
        const evf4* r1 = reinterpret_cast<const evf4*>(sw2 + (4*jq + 1) * DD);
        const evf4* r2 = reinterpret_cast<const evf4*>(sw2 + (4*jq + 2) * DD);
        const evf4* r3 = reinterpret_cast<const evf4*>(sw2 + (4*jq + 3) * DD);
        float a00 = 0.0f, a01 = 0.0f, a02 = 0.0f, a03 = 0.0f;
#pragma unroll
        for (int k4 = 0; k4 < 16; ++k4) {
            const evf4 w0 = r0[k4], w1v = r1[k4], w2v = r2[k4], w3v = r3[k4];
            const float h0 = acc[4*k4+0], h1v = acc[4*k4+1],
                        h2v = acc[4*k4+2], h3v = acc[4*k4+3];
            a00 = fmaf(h0, w0.x, a00); a00 = fmaf(h1v, w0.y, a00);
            a00 = fmaf(h2v, w0.z, a00); a00 = fmaf(h3v, w0.w, a00);
            a01 = fmaf(h0, w1v.x, a01); a01 = fmaf(h1v, w1v.y, a01);
            a01 = fmaf(h2v, w1v.z, a01); a01 = fmaf(h3v, w1v.w, a01);
            a02 = fmaf(h0, w2v.x, a02); a02 = fmaf(h1v, w2v.y, a02);
            a02 = fmaf(h2v, w2v.z, a02); a02 = fmaf(h3v, w2v.w, a02);
            a03 = fmaf(h0, w3v.x, a03); a03 = fmaf(h1v, w3v.y, a03);
            a03 = fmaf(h2v, w3v.z, a03); a03 = fmaf(h3v, w3v.w, a03);
        }
        float hv[4] = {a00, a01, a02, a03};
#pragma unroll
        for (int u = 0; u < 4; ++u) {
            const int jj = 4*jq + u;
            float sc = g2c[jj] * (1.0f / sqrtf(v2c[jj] + 1e-5f));
            float h  = fmaf(hv[u] + b2c[jj] - m2c[jj], sc, be2c[jj]);
            h = fmaxf(h, 0.0f);
            hv[u] = h;
            s = fmaf(h, w3c[jj], s);
        }
        o[jq] = make_float4(hv[0], hv[1], hv[2], hv[3]);
    }
    s += TO_CSF(b3)[0];
    const float score = fmaxf(s, 0.0f);

    // sigmoid(score) > 0.5 via XLA-style logistic expansion (score >= 0)
    const bool on = (0.5f + 0.5f * tanhf(0.5f * score)) > 0.5f;

    // ---- Phase C: geometry + 4 output stores + ballots per plane ----
    const csf4 pp = TO_CSF4(packed);
#pragma unroll 1
    for (int p2 = 0; p2 < NP; ++p2) {
        const evf4 nrm = pp[p2*3+0];
        const evf4 mn  = pp[p2*3+1];
        const evf4 mx  = pp[p2*3+2];
        float d = fabsf(fmaf(c2, nrm.z, fmaf(c1, nrm.y, c0 * nrm.x)) - nrm.w);
        bool ok0 = (mx.x == 0.0f) | ((c0 >= mn.x) & (c0 < mx.x));
        bool ok1 = (mx.y == 0.0f) | ((c1 >= mn.y) & (c1 < mx.y));
        bool ok2 = (mx.z == 0.0f) | ((c2 >= mn.z) & (c2 < mx.z));
        bool mk  = ok0 & ok1 & ok2 & (d < 0.1f);
        const size_t idx = (size_t)p2 * NPTS + n;
        const bool mon  = mk & on;
        const bool moff = mk & (!on);
        out_mask[idx] = mk ? 1.0f : 0.0f;
        out_sm[idx]   = mk ? score : 0.0f;
        out_on[idx]   = mon ? 1.0f : 0.0f;
        out_off[idx]  = moff ? 1.0f : 0.0f;
        unsigned long long bOn  = __ballot(mon);
        unsigned long long bOff = __ballot(moff);
        if (lane == 0) {
            hitOn [(size_t)p2 * NWORDS + word] = bOn;
            hitOff[(size_t)p2 * NWORDS + word] = bOff;
        }
    }
}

// ---------------------------------------------------------------------------
// Pool: masked max of h2 per plane, register-accumulated per block, then
// atomicMax(int) into out_feats (non-negative IEEE floats compare as signed
// ints; h2 >= 0; zero-init by prep -> exact where(any,max,0) semantics).
// Wave w owns planes [32w,32w+32); lane = dim; hit loop is wave-uniform.
// tile[n*64+lane]: 2-way bank alias = free (m136).
// ---------------------------------------------------------------------------
__global__ __launch_bounds__(256) void pool_kernel(
    const float* __restrict__ h2,
    const unsigned long long* __restrict__ hitOn,
    const unsigned long long* __restrict__ hitOff,
    int* __restrict__ out_feats_i)
{
    __shared__ float tile[128 * DD];                 // 32 KB
    __shared__ unsigned long long bm[2][NP][2];      // 4 KB
    const int t = threadIdx.x;
    const int lane = t & 63;
    const int wv = t >> 6;

    float accOn[32], accOff[32];
#pragma unroll
    for (int i = 0; i < 32; ++i) { accOn[i] = 0.0f; accOff[i] = 0.0f; }

    for (int cc = 0; cc < 4; ++cc) {
        const int chunk = blockIdx.x * 4 + cc;       // 0..2047
        const int base  = chunk * 128;
        const float4* src = reinterpret_cast<const float4*>(h2 + (size_t)base * DD);
        float4* dst = reinterpret_cast<float4*>(tile);
#pragma unroll
        for (int q = 0; q < 8; ++q) dst[t + q * 256] = src[t + q * 256];
        {
            const int p = t & 127;
            const int half = t >> 7;
            const unsigned long long* hsrc = half ? hitOff : hitOn;
            const int w0 = chunk * 2;
            bm[half][p][0] = hsrc[(size_t)p * NWORDS + w0 + 0];
            bm[half][p][1] = hsrc[(size_t)p * NWORDS + w0 + 1];
        }
        __syncthreads();

#pragma unroll
        for (int i = 0; i < 32; ++i) {
            const int p = wv * 32 + i;
            unsigned long long m;
            m = bm[0][p][0];
            while (m) { int nn = __builtin_ctzll(m); m &= m - 1;
                        accOn[i]  = fmaxf(accOn[i],  tile[nn * DD + lane]); }
            m = bm[0][p][1];
            while (m) { int nn = __builtin_ctzll(m); m &= m - 1;
                        accOn[i]  = fmaxf(accOn[i],  tile[(64 + nn) * DD + lane]); }
            m = bm[1][p][0];
            while (m) { int nn = __builtin_ctzll(m); m &= m - 1;
                        accOff[i] = fmaxf(accOff[i], tile[nn * DD + lane]); }
            m = bm[1][p][1];
            while (m) { int nn = __builtin_ctzll(m); m &= m - 1;
                        accOff[i] = fmaxf(accOff[i], tile[(64 + nn) * DD + lane]); }
        }
        __syncthreads();
    }
#pragma unroll
    for (int i = 0; i < 32; ++i) {
        const int p = wv * 32 + i;
        if (accOn[i]  != 0.0f) atomicMax(&out_feats_i[p * DD + lane],            __float_as_int(accOn[i]));
        if (accOff[i] != 0.0f) atomicMax(&out_feats_i[NP * DD + p * DD + lane],  __float_as_int(accOff[i]));
    }
}

extern "C" void kernel_launch(void* const* d_in, const int* in_sizes, int n_in,
                              void* d_out, int out_size, void* d_ws, size_t ws_size,
                              hipStream_t stream) {
    const float* feature      = (const float*)d_in[0];
    const float* feature_geo  = (const float*)d_in[1];
    const float* xyz          = (const float*)d_in[2];
    const float* centers      = (const float*)d_in[3];
    const float* plane_center = (const float*)d_in[4];
    const float* plane_normal = (const float*)d_in[5];
    const float* pmin         = (const float*)d_in[6];
    const float* pmax         = (const float*)d_in[7];
    const float* w1 = (const float*)d_in[8];
    const float* b1 = (const float*)d_in[9];
    const float* g1 = (const float*)d_in[10];
    const float* be1 = (const float*)d_in[11];
    const float* m1 = (const float*)d_in[12];
    const float* v1 = (const float*)d_in[13];
    const float* w2 = (const float*)d_in[14];
    const float* b2 = (const float*)d_in[15];
    const float* g2 = (const float*)d_in[16];
    const float* be2 = (const float*)d_in[17];
    const float* m2 = (const float*)d_in[18];
    const float* v2 = (const float*)d_in[19];
    const float* w3 = (const float*)d_in[20];
    const float* b3 = (const float*)d_in[21];

    float* out = (float*)d_out;
    const size_t PN = (size_t)NP * NPTS;
    float* out_sm    = out;
    float* out_mask  = out + PN;
    float* out_on    = out + 2 * PN;
    float* out_off   = out + 3 * PN;
    float* out_feats = out + 4 * PN;

    // workspace carve (~73 MB)
    float* h2     = (float*)d_ws;                                // N*64 f32 (64 MB)
    unsigned long long* hitOn  = (unsigned long long*)(h2 + (size_t)NPTS * DD);
    unsigned long long* hitOff = hitOn + (size_t)NP * NWORDS;
    float* packed = (float*)(hitOff + (size_t)NP * NWORDS);      // P*12 f32
    float* w2T    = packed + NP * 12;                            // 64*64 f32

    prep_kernel<<<64, 256, 0, stream>>>(
        plane_center, plane_normal, pmin, pmax, w2, packed, w2T, out_feats);
    fused_kernel<<<NPTS / 256, 256, 0, stream>>>(
        feature, feature_geo, xyz, centers, packed,
        w1, b1, g1, be1, m1, v1, w2T, b2, g2, be2, m2, v2, w3, b3,
        h2, out_sm, out_mask, out_on, out_off, hitOn, hitOff);
    pool_kernel<<<512, 256, 0, stream>>>(h2, hitOn, hitOff, (int*)out_feats);
}

// Round 4
// 838.104 us; speedup vs baseline: 1.2126x; 1.0852x over previous
//
#include <hip/hip_runtime.h>
#include <hip/hip_bf16.h>
#include <math.h>

// Problem constants (fixed by the reference file)
#define NPTS 262144
#define NP   128
#define DD   64
#define NWORDS (NPTS / 64)   // 4096 u64 ballot words per plane

// AS(4) scalar pointers for small uniform reads (planes/BN). R7 lesson: use
// POD ext_vector for AS(4) vectors (HIP float4 ctors break the host pass).
#define AS4 __attribute__((address_space(4)))
typedef float evf4 __attribute__((ext_vector_type(4)));
typedef AS4 const float* csf;
typedef AS4 const evf4*  csf4;
#define TO_CSF(p)  ((csf)(unsigned long long)(const void*)(p))
#define TO_CSF4(p) ((csf4)(unsigned long long)(const void*)(p))

// ---------------------------------------------------------------------------
// Prep: pack plane params [P][12] (normal.xyz+offs | min.xyz | max.xyz),
// transpose w2 -> w2T[j][k], zero out_feats for the atomic-max pool.
// ---------------------------------------------------------------------------
__global__ __launch_bounds__(256) void prep_kernel(
    const float* __restrict__ plane_center, const float* __restrict__ plane_normal,
    const float* __restrict__ pmin, const float* __restrict__ pmax,
    const float* __restrict__ w2,
    float* __restrict__ packed, float* __restrict__ w2T,
    float* __restrict__ out_feats)
{
    const int t = threadIdx.x;
    out_feats[blockIdx.x * 256 + t] = 0.0f;          // grid = 64 blocks
    if (blockIdx.x == 0 && t < NP) {
        float n0 = plane_normal[t*3+0], n1 = plane_normal[t*3+1], n2 = plane_normal[t*3+2];
        float c0 = plane_center[t*3+0], c1 = plane_center[t*3+1], c2 = plane_center[t*3+2];
        float off = (c0*n0 + c1*n1) + c2*n2;          // matches jnp.sum order
        float4* pp = reinterpret_cast<float4*>(packed) + t * 3;
        pp[0] = make_float4(n0, n1, n2, off);
        pp[1] = make_float4(pmin[t*3+0], pmin[t*3+1], pmin[t*3+2], 0.0f);
        pp[2] = make_float4(pmax[t*3+0], pmax[t*3+1], pmax[t*3+2], 0.0f);
    }
    if (blockIdx.x == 1) {
#pragma unroll
        for (int u = 0; u < 16; ++u) {
            const int e = u * 256 + t;               // e = j*64 + k
            const int j = e >> 6, k = e & 63;
            w2T[e] = w2[k * DD + j];
        }
    }
}

// ---------------------------------------------------------------------------
// Fused per-point kernel: EXACT R9 revert (the 832us-verified version).
// R10-R12 post-mortem: every restructure of the fc phase lost. R10/R11:
// allocator caps at 128 VGPR regardless of launch_bounds/waves_per_eu ->
// 2-pt-all-dims spills ~1GB scratch. R12: dim-split halved Phase A ds_reads
// but runtime-indexed acc[] (rule #20) went to scratch (+233MB WRITE) AND
// the LDS halving gained ~0 -> fc is NOT LDS-return-bound. This structure
// (1 pt/thread, LDS-staged weights, de-jammed phases) is the verified local
// optimum at ~330us. absmax 2.98e-8.
// ---------------------------------------------------------------------------
__global__ __launch_bounds__(256) void fused_kernel(
    const float* __restrict__ feature, const float* __restrict__ feature_geo,
    const float* __restrict__ xyz, const float* __restrict__ centers,
    const float* __restrict__ packed,
    const float* __restrict__ w1, const float* __restrict__ b1,
    const float* __restrict__ g1, const float* __restrict__ be1,
    const float* __restrict__ m1, const float* __restrict__ v1,
    const float* __restrict__ w2T, const float* __restrict__ b2,
    const float* __restrict__ g2, const float* __restrict__ be2,
    const float* __restrict__ m2, const float* __restrict__ v2,
    const float* __restrict__ w3, const float* __restrict__ b3,
    float* __restrict__ h2_out,
    float* __restrict__ out_sm, float* __restrict__ out_mask,
    float* __restrict__ out_on, float* __restrict__ out_off,
    unsigned long long* __restrict__ hitOn, unsigned long long* __restrict__ hitOff)
{
    __shared__ float sw1[128 * DD];   // 32 KB, row-major [k][j] like w1
    __shared__ float sw2[DD * DD];    // 16 KB, w2T layout [j][k]
    const int t = threadIdx.x;
    const int n = blockIdx.x * 256 + t;
    const int lane = t & 63;
    const int word = n >> 6;

    // stage weights (coalesced float4; 12 per thread)
    {
        const float4* s1 = reinterpret_cast<const float4*>(w1);
        const float4* s2 = reinterpret_cast<const float4*>(w2T);
        float4* d1 = reinterpret_cast<float4*>(sw1);
        float4* d2 = reinterpret_cast<float4*>(sw2);
#pragma unroll
        for (int k = 0; k < 8; ++k) d1[t + k * 256] = s1[t + k * 256];
#pragma unroll
        for (int k = 0; k < 4; ++k) d2[t + k * 256] = s2[t + k * 256];
    }

    // cloud coords (issue early; used in Phase C)
    const csf cc = TO_CSF(centers);
    const float c0 = xyz[n*3+0] + cc[0];
    const float c1 = xyz[n*3+1] + cc[1];
    const float c2 = xyz[n*3+2] + cc[2];

    __syncthreads();

    float acc[DD];
#pragma unroll
    for (int j = 0; j < DD; ++j) acc[j] = 0.0f;

    // ---- Phase A: fc1 from LDS (q rolled, j-blocks as 16x b128) ----
    const float4* fA = reinterpret_cast<const float4*>(feature) + (size_t)n * 16;
    const float4* fB = reinterpret_cast<const float4*>(feature_geo) + (size_t)n * 16;
#pragma unroll 1
    for (int q = 0; q < 16; ++q) {
        const float4 fv = fA[q];
        const evf4* wr = reinterpret_cast<const evf4*>(sw1 + q * 4 * DD);
#pragma unroll
        for (int j4 = 0; j4 < 16; ++j4) { const evf4 w = wr[j4];
            acc[4*j4+0] = fmaf(fv.x, w.x, acc[4*j4+0]);
            acc[4*j4+1] = fmaf(fv.x, w.y, acc[4*j4+1]);
            acc[4*j4+2] = fmaf(fv.x, w.z, acc[4*j4+2]);
            acc[4*j4+3] = fmaf(fv.x, w.w, acc[4*j4+3]); }
#pragma unroll
        for (int j4 = 0; j4 < 16; ++j4) { const evf4 w = wr[16 + j4];
            acc[4*j4+0] = fmaf(fv.y, w.x, acc[4*j4+0]);
            acc[4*j4+1] = fmaf(fv.y, w.y, acc[4*j4+1]);
            acc[4*j4+2] = fmaf(fv.y, w.z, acc[4*j4+2]);
            acc[4*j4+3] = fmaf(fv.y, w.w, acc[4*j4+3]); }
#pragma unroll
        for (int j4 = 0; j4 < 16; ++j4) { const evf4 w = wr[32 + j4];
            acc[4*j4+0] = fmaf(fv.z, w.x, acc[4*j4+0]);
            acc[4*j4+1] = fmaf(fv.z, w.y, acc[4*j4+1]);
            acc[4*j4+2] = fmaf(fv.z, w.z, acc[4*j4+2]);
            acc[4*j4+3] = fmaf(fv.z, w.w, acc[4*j4+3]); }
#pragma unroll
        for (int j4 = 0; j4 < 16; ++j4) { const evf4 w = wr[48 + j4];
            acc[4*j4+0] = fmaf(fv.w, w.x, acc[4*j4+0]);
            acc[4*j4+1] = fmaf(fv.w, w.y, acc[4*j4+1]);
            acc[4*j4+2] = fmaf(fv.w, w.z, acc[4*j4+2]);
            acc[4*j4+3] = fmaf(fv.w, w.w, acc[4*j4+3]); }
    }
#pragma unroll 1
    for (int q = 0; q < 16; ++q) {
        const float4 fv = fB[q];
        const evf4* wr = reinterpret_cast<const evf4*>(sw1 + (DD + q * 4) * DD);
#pragma unroll
        for (int j4 = 0; j4 < 16; ++j4) { const evf4 w = wr[j4];
            acc[4*j4+0] = fmaf(fv.x, w.x, acc[4*j4+0]);
            acc[4*j4+1] = fmaf(fv.x, w.y, acc[4*j4+1]);
            acc[4*j4+2] = fmaf(fv.x, w.z, acc[4*j4+2]);
            acc[4*j4+3] = fmaf(fv.x, w.w, acc[4*j4+3]); }
#pragma unroll
        for (int j4 = 0; j4 < 16; ++j4) { const evf4 w = wr[16 + j4];
            acc[4*j4+0] = fmaf(fv.y, w.x, acc[4*j4+0]);
            acc[4*j4+1] = fmaf(fv.y, w.y, acc[4*j4+1]);
            acc[4*j4+2] = fmaf(fv.y, w.z, acc[4*j4+2]);
            acc[4*j4+3] = fmaf(fv.y, w.w, acc[4*j4+3]); }
#pragma unroll
        for (int j4 = 0; j4 < 16; ++j4) { const evf4 w = wr[32 + j4];
            acc[4*j4+0] = fmaf(fv.z, w.x, acc[4*j4+0]);
            acc[4*j4+1] = fmaf(fv.z, w.y, acc[4*j4+1]);
            acc[4*j4+2] = fmaf(fv.z, w.z, acc[4*j4+2]);
            acc[4*j4+3] = fmaf(fv.z, w.w, acc[4*j4+3]); }
#pragma unroll
        for (int j4 = 0; j4 < 16; ++j4) { const evf4 w = wr[48 + j4];
            acc[4*j4+0] = fmaf(fv.w, w.x, acc[4*j4+0]);
            acc[4*j4+1] = fmaf(fv.w, w.y, acc[4*j4+1]);
            acc[4*j4+2] = fmaf(fv.w, w.z, acc[4*j4+2]);
            acc[4*j4+3] = fmaf(fv.w, w.w, acc[4*j4+3]); }
    }
    // BN1 + ReLU in place (exact same arithmetic/order as R3-R9)
    {
        const csf g1c = TO_CSF(g1), v1c = TO_CSF(v1), b1c = TO_CSF(b1),
                  m1c = TO_CSF(m1), be1c = TO_CSF(be1);
#pragma unroll
        for (int j = 0; j < DD; ++j) {
            float sc = g1c[j] * (1.0f / sqrtf(v1c[j] + 1e-5f));
            float h  = fmaf(acc[j] + b1c[j] - m1c[j], sc, be1c[j]);
            acc[j] = fmaxf(h, 0.0f);
        }
    }

    // ---- Phase B: fc2 from LDS w2T rows + BN2 + ReLU + fc3 + h2 store ----
    const csf g2c = TO_CSF(g2), v2c = TO_CSF(v2), b2c = TO_CSF(b2),
              m2c = TO_CSF(m2), be2c = TO_CSF(be2), w3c = TO_CSF(w3);
    float s = 0.0f;
    float4* o = reinterpret_cast<float4*>(h2_out) + (size_t)n * 16;
#pragma unroll 1
    for (int jq = 0; jq < 16; ++jq) {
        const evf4* r0 = reinterpret_cast<const evf4*>(sw2 + (4*jq + 0) * DD);
        const evf4* r1 = reinterpret_cast<const evf4*>(sw2 + (4*jq + 1) * DD);
        const evf4* r2 = reinterpret_cast<const evf4*>(sw2 + (4*jq + 2) * DD);
        const evf4* r3 = reinterpret_cast<const evf4*>(sw2 + (4*jq + 3) * DD);
        float a0 = 0.0f, a1 = 0.0f, a2 = 0.0f, a3 = 0.0f;
#pragma unroll
        for (int k4 = 0; k4 < 16; ++k4) {
            const evf4 w0 = r0[k4], w1v = r1[k4], w2v = r2[k4], w3v = r3[k4];
            const float h0 = acc[4*k4+0], h1v = acc[4*k4+1],
                        h2v = acc[4*k4+2], h3v = acc[4*k4+3];
            a0 = fmaf(h0, w0.x, a0); a0 = fmaf(h1v, w0.y, a0);
            a0 = fmaf(h2v, w0.z, a0); a0 = fmaf(h3v, w0.w, a0);
            a1 = fmaf(h0, w1v.x, a1); a1 = fmaf(h1v, w1v.y, a1);
            a1 = fmaf(h2v, w1v.z, a1); a1 = fmaf(h3v, w1v.w, a1);
            a2 = fmaf(h0, w2v.x, a2); a2 = fmaf(h1v, w2v.y, a2);
            a2 = fmaf(h2v, w2v.z, a2); a2 = fmaf(h3v, w2v.w, a2);
            a3 = fmaf(h0, w3v.x, a3); a3 = fmaf(h1v, w3v.y, a3);
            a3 = fmaf(h2v, w3v.z, a3); a3 = fmaf(h3v, w3v.w, a3);
        }
        float hv[4] = {a0, a1, a2, a3};
#pragma unroll
        for (int u = 0; u < 4; ++u) {
            const int jj = 4*jq + u;
            float sc = g2c[jj] * (1.0f / sqrtf(v2c[jj] + 1e-5f));
            float h  = fmaf(hv[u] + b2c[jj] - m2c[jj], sc, be2c[jj]);
            h = fmaxf(h, 0.0f);
            hv[u] = h;
            s = fmaf(h, w3c[jj], s);
        }
        o[jq] = make_float4(hv[0], hv[1], hv[2], hv[3]);
    }
    s += TO_CSF(b3)[0];
    const float score = fmaxf(s, 0.0f);

    // sigmoid(score) > 0.5 via XLA-style logistic expansion (score >= 0)
    const bool on = (0.5f + 0.5f * tanhf(0.5f * score)) > 0.5f;

    // ---- Phase C: geometry + 4 output stores + ballots per plane ----
    const csf4 pp = TO_CSF4(packed);
#pragma unroll 1
    for (int p = 0; p < NP; ++p) {
        const evf4 nrm = pp[p*3+0];
        const evf4 mn  = pp[p*3+1];
        const evf4 mx  = pp[p*3+2];
        float d = fabsf(fmaf(c2, nrm.z, fmaf(c1, nrm.y, c0 * nrm.x)) - nrm.w);
        bool ok0 = (mx.x == 0.0f) | ((c0 >= mn.x) & (c0 < mx.x));
        bool ok1 = (mx.y == 0.0f) | ((c1 >= mn.y) & (c1 < mx.y));
        bool ok2 = (mx.z == 0.0f) | ((c2 >= mn.z) & (c2 < mx.z));
        bool mk  = ok0 & ok1 & ok2 & (d < 0.1f);
        const size_t idx = (size_t)p * NPTS + n;
        const bool mon  = mk & on;
        const bool moff = mk & (!on);
        out_mask[idx] = mk ? 1.0f : 0.0f;
        out_sm[idx]   = mk ? score : 0.0f;
        out_on[idx]   = mon ? 1.0f : 0.0f;
        out_off[idx]  = moff ? 1.0f : 0.0f;
        unsigned long long bOn  = __ballot(mon);
        unsigned long long bOff = __ballot(moff);
        if (lane == 0) {
            hitOn [(size_t)p * NWORDS + word] = bOn;
            hitOff[(size_t)p * NWORDS + word] = bOff;
        }
    }
}

// ---------------------------------------------------------------------------
// Pool, round-13: LATENCY ATTACK. The hit loop was one ds_read_b32 ->
// lgkmcnt(0) -> fmax -> branch per hit: full ~120cyc LDS latency per hit,
// serial, with only 2 blocks/CU of TLP (512 blocks). ~160us for 67MB of
// reads = latency-bound, not BW/VALU. Fixes:
//  (a) grid 512 -> 1024 (2 chunks/block; 36.25KB LDS -> 4 blocks/CU
//      resident = 2x TLP to overlap waves' serial chains),
//  (b) dual dependence chains: words 0 and 1 of each plane interleaved, so
//      two loads are in flight per waitcnt (~halves latency per hit).
// fmax is commutative/associative (h2 has no NaN) -> result identical.
// All masks wave-uniform -> no divergence. Atomics 2x (8.4M -> 16.8M) into
// a 64KB L2-resident region: acceptable. Wave w owns planes [32w,32w+32);
// lane = dim. tile[n*64+lane]: 2-way bank alias = free (m136).
// ---------------------------------------------------------------------------
__global__ __launch_bounds__(256) void pool_kernel(
    const float* __restrict__ h2,
    const unsigned long long* __restrict__ hitOn,
    const unsigned long long* __restrict__ hitOff,
    int* __restrict__ out_feats_i)
{
    __shared__ float tile[128 * DD];                 // 32 KB
    __shared__ unsigned long long bm[2][NP][2];      // 4 KB
    const int t = threadIdx.x;
    const int lane = t & 63;
    const int wv = t >> 6;

    float accOn[32], accOff[32];
#pragma unroll
    for (int i = 0; i < 32; ++i) { accOn[i] = 0.0f; accOff[i] = 0.0f; }

    for (int cc = 0; cc < 2; ++cc) {
        const int chunk = blockIdx.x * 2 + cc;       // 0..2047
        const int base  = chunk * 128;
        const float4* src = reinterpret_cast<const float4*>(h2 + (size_t)base * DD);
        float4* dst = reinterpret_cast<float4*>(tile);
#pragma unroll
        for (int q = 0; q < 8; ++q) dst[t + q * 256] = src[t + q * 256];
        {
            const int p = t & 127;
            const int half = t >> 7;
            const unsigned long long* hsrc = half ? hitOff : hitOn;
            const int w0 = chunk * 2;
            bm[half][p][0] = hsrc[(size_t)p * NWORDS + w0 + 0];
            bm[half][p][1] = hsrc[(size_t)p * NWORDS + w0 + 1];
        }
        __syncthreads();

#pragma unroll
        for (int i = 0; i < 32; ++i) {
            const int p = wv * 32 + i;
            // ON: interleave word0/word1 chains (independent loads)
            {
                unsigned long long m0 = bm[0][p][0], m1 = bm[0][p][1];
                float a = accOn[i];
                while (m0 && m1) {
                    int na = __builtin_ctzll(m0); m0 &= m0 - 1;
                    int nb = __builtin_ctzll(m1); m1 &= m1 - 1;
                    float va = tile[na * DD + lane];
                    float vb = tile[(64 + nb) * DD + lane];
                    a = fmaxf(a, va); a = fmaxf(a, vb);
                }
                while (m0) { int na = __builtin_ctzll(m0); m0 &= m0 - 1;
                             a = fmaxf(a, tile[na * DD + lane]); }
                while (m1) { int nb = __builtin_ctzll(m1); m1 &= m1 - 1;
                             a = fmaxf(a, tile[(64 + nb) * DD + lane]); }
                accOn[i] = a;
            }
            // OFF: same structure
            {
                unsigned long long m0 = bm[1][p][0], m1 = bm[1][p][1];
                float a = accOff[i];
                while (m0 && m1) {
                    int na = __builtin_ctzll(m0); m0 &= m0 - 1;
                    int nb = __builtin_ctzll(m1); m1 &= m1 - 1;
                    float va = tile[na * DD + lane];
                    float vb = tile[(64 + nb) * DD + lane];
                    a = fmaxf(a, va); a = fmaxf(a, vb);
                }
                while (m0) { int na = __builtin_ctzll(m0); m0 &= m0 - 1;
                             a = fmaxf(a, tile[na * DD + lane]); }
                while (m1) { int nb = __builtin_ctzll(m1); m1 &= m1 - 1;
                             a = fmaxf(a, tile[(64 + nb) * DD + lane]); }
                accOff[i] = a;
            }
        }
        __syncthreads();
    }
#pragma unroll
    for (int i = 0; i < 32; ++i) {
        const int p = wv * 32 + i;
        if (accOn[i]  != 0.0f) atomicMax(&out_feats_i[p * DD + lane],            __float_as_int(accOn[i]));
        if (accOff[i] != 0.0f) atomicMax(&out_feats_i[NP * DD + p * DD + lane],  __float_as_int(accOff[i]));
    }
}

extern "C" void kernel_launch(void* const* d_in, const int* in_sizes, int n_in,
                              void* d_out, int out_size, void* d_ws, size_t ws_size,
                              hipStream_t stream) {
    const float* feature      = (const float*)d_in[0];
    const float* feature_geo  = (const float*)d_in[1];
    const float* xyz          = (const float*)d_in[2];
    const float* centers      = (const float*)d_in[3];
    const float* plane_center = (const float*)d_in[4];
    const float* plane_normal = (const float*)d_in[5];
    const float* pmin         = (const float*)d_in[6];
    const float* pmax         = (const float*)d_in[7];
    const float* w1 = (const float*)d_in[8];
    const float* b1 = (const float*)d_in[9];
    const float* g1 = (const float*)d_in[10];
    const float* be1 = (const float*)d_in[11];
    const float* m1 = (const float*)d_in[12];
    const float* v1 = (const float*)d_in[13];
    const float* w2 = (const float*)d_in[14];
    const float* b2 = (const float*)d_in[15];
    const float* g2 = (const float*)d_in[16];
    const float* be2 = (const float*)d_in[17];
    const float* m2 = (const float*)d_in[18];
    const float* v2 = (const float*)d_in[19];
    const float* w3 = (const float*)d_in[20];
    const float* b3 = (const float*)d_in[21];

    float* out = (float*)d_out;
    const size_t PN = (size_t)NP * NPTS;
    float* out_sm    = out;
    float* out_mask  = out + PN;
    float* out_on    = out + 2 * PN;
    float* out_off   = out + 3 * PN;
    float* out_feats = out + 4 * PN;

    // workspace carve (~73 MB)
    float* h2     = (float*)d_ws;                                // N*64 f32 (64 MB)
    unsigned long long* hitOn  = (unsigned long long*)(h2 + (size_t)NPTS * DD);
    unsigned long long* hitOff = hitOn + (size_t)NP * NWORDS;
    float* packed = (float*)(hitOff + (size_t)NP * NWORDS);      // P*12 f32
    float* w2T    = packed + NP * 12;                            // 64*64 f32

    prep_kernel<<<64, 256, 0, stream>>>(
        plane_center, plane_normal, pmin, pmax, w2, packed, w2T, out_feats);
    fused_kernel<<<NPTS / 256, 256, 0, stream>>>(
        feature, feature_geo, xyz, centers, packed,
        w1, b1, g1, be1, m1, v1, w2T, b2, g2, be2, m2, v2, w3, b3,
        h2, out_sm, out_mask, out_on, out_off, hitOn, hitOff);
    pool_kernel<<<1024, 256, 0, stream>>>(h2, hitOn, hitOff, (int*)out_feats);
}

// Round 5
// 824.107 us; speedup vs baseline: 1.2332x; 1.0170x over previous
//
#include <hip/hip_runtime.h>
#include <hip/hip_bf16.h>
#include <math.h>

// Problem constants (fixed by the reference file)
#define NPTS 262144
#define NP   128
#define DD   64
#define NWORDS (NPTS / 64)   // 4096 u64 ballot words per plane

// AS(4) scalar pointers for small uniform reads (planes/BN). R7 lesson: use
// POD ext_vector for AS(4) vectors (HIP float4 ctors break the host pass).
#define AS4 __attribute__((address_space(4)))
typedef float evf4 __attribute__((ext_vector_type(4)));
typedef AS4 const float* csf;
typedef AS4 const evf4*  csf4;
#define TO_CSF(p)  ((csf)(unsigned long long)(const void*)(p))
#define TO_CSF4(p) ((csf4)(unsigned long long)(const void*)(p))

// ---------------------------------------------------------------------------
// Prep: pack plane params [P][12] (normal.xyz+offs | min.xyz | max.xyz),
// transpose w2 -> w2T[j][k], zero out_feats for the atomic-max pool.
// ---------------------------------------------------------------------------
__global__ __launch_bounds__(256) void prep_kernel(
    const float* __restrict__ plane_center, const float* __restrict__ plane_normal,
    const float* __restrict__ pmin, const float* __restrict__ pmax,
    const float* __restrict__ w2,
    float* __restrict__ packed, float* __restrict__ w2T,
    float* __restrict__ out_feats)
{
    const int t = threadIdx.x;
    out_feats[blockIdx.x * 256 + t] = 0.0f;          // grid = 64 blocks
    if (blockIdx.x == 0 && t < NP) {
        float n0 = plane_normal[t*3+0], n1 = plane_normal[t*3+1], n2 = plane_normal[t*3+2];
        float c0 = plane_center[t*3+0], c1 = plane_center[t*3+1], c2 = plane_center[t*3+2];
        float off = (c0*n0 + c1*n1) + c2*n2;          // matches jnp.sum order
        float4* pp = reinterpret_cast<float4*>(packed) + t * 3;
        pp[0] = make_float4(n0, n1, n2, off);
        pp[1] = make_float4(pmin[t*3+0], pmin[t*3+1], pmin[t*3+2], 0.0f);
        pp[2] = make_float4(pmax[t*3+0], pmax[t*3+1], pmax[t*3+2], 0.0f);
    }
    if (blockIdx.x == 1) {
#pragma unroll
        for (int u = 0; u < 16; ++u) {
            const int e = u * 256 + t;               // e = j*64 + k
            const int j = e >> 6, k = e & 63;
            w2T[e] = w2[k * DD + j];
        }
    }
}

// ---------------------------------------------------------------------------
// Fused per-point kernel: EXACT R9 form (the 832us-verified version).
// R10-R12 post-mortem: every restructure of the fc phase lost (allocator
// caps at 128 VGPR -> spills; dim-split -> runtime-indexed scratch AND the
// LDS-read halving gained ~0, falsifying the LDS-return-BW theory). This
// structure (1 pt/thread, LDS-staged weights, de-jammed phases) is the
// verified local optimum at ~330us. absmax 2.98e-8.
// ---------------------------------------------------------------------------
__global__ __launch_bounds__(256) void fused_kernel(
    const float* __restrict__ feature, const float* __restrict__ feature_geo,
    const float* __restrict__ xyz, const float* __restrict__ centers,
    const float* __restrict__ packed,
    const float* __restrict__ w1, const float* __restrict__ b1,
    const float* __restrict__ g1, const float* __restrict__ be1,
    const float* __restrict__ m1, const float* __restrict__ v1,
    const float* __restrict__ w2T, const float* __restrict__ b2,
    const float* __restrict__ g2, const float* __restrict__ be2,
    const float* __restrict__ m2, const float* __restrict__ v2,
    const float* __restrict__ w3, const float* __restrict__ b3,
    float* __restrict__ h2_out,
    float* __restrict__ out_sm, float* __restrict__ out_mask,
    float* __restrict__ out_on, float* __restrict__ out_off,
    unsigned long long* __restrict__ hitOn, unsigned long long* __restrict__ hitOff)
{
    __shared__ float sw1[128 * DD];   // 32 KB, row-major [k][j] like w1
    __shared__ float sw2[DD * DD];    // 16 KB, w2T layout [j][k]
    const int t = threadIdx.x;
    const int n = blockIdx.x * 256 + t;
    const int lane = t & 63;
    const int word = n >> 6;

    // stage weights (coalesced float4; 12 per thread)
    {
        const float4* s1 = reinterpret_cast<const float4*>(w1);
        const float4* s2 = reinterpret_cast<const float4*>(w2T);
        float4* d1 = reinterpret_cast<float4*>(sw1);
        float4* d2 = reinterpret_cast<float4*>(sw2);
#pragma unroll
        for (int k = 0; k < 8; ++k) d1[t + k * 256] = s1[t + k * 256];
#pragma unroll
        for (int k = 0; k < 4; ++k) d2[t + k * 256] = s2[t + k * 256];
    }

    // cloud coords (issue early; used in Phase C)
    const csf cc = TO_CSF(centers);
    const float c0 = xyz[n*3+0] + cc[0];
    const float c1 = xyz[n*3+1] + cc[1];
    const float c2 = xyz[n*3+2] + cc[2];

    __syncthreads();

    float acc[DD];
#pragma unroll
    for (int j = 0; j < DD; ++j) acc[j] = 0.0f;

    // ---- Phase A: fc1 from LDS (q rolled, j-blocks as 16x b128) ----
    const float4* fA = reinterpret_cast<const float4*>(feature) + (size_t)n * 16;
    const float4* fB = reinterpret_cast<const float4*>(feature_geo) + (size_t)n * 16;
#pragma unroll 1
    for (int q = 0; q < 16; ++q) {
        const float4 fv = fA[q];
        const evf4* wr = reinterpret_cast<const evf4*>(sw1 + q * 4 * DD);
#pragma unroll
        for (int j4 = 0; j4 < 16; ++j4) { const evf4 w = wr[j4];
            acc[4*j4+0] = fmaf(fv.x, w.x, acc[4*j4+0]);
            acc[4*j4+1] = fmaf(fv.x, w.y, acc[4*j4+1]);
            acc[4*j4+2] = fmaf(fv.x, w.z, acc[4*j4+2]);
            acc[4*j4+3] = fmaf(fv.x, w.w, acc[4*j4+3]); }
#pragma unroll
        for (int j4 = 0; j4 < 16; ++j4) { const evf4 w = wr[16 + j4];
            acc[4*j4+0] = fmaf(fv.y, w.x, acc[4*j4+0]);
            acc[4*j4+1] = fmaf(fv.y, w.y, acc[4*j4+1]);
            acc[4*j4+2] = fmaf(fv.y, w.z, acc[4*j4+2]);
            acc[4*j4+3] = fmaf(fv.y, w.w, acc[4*j4+3]); }
#pragma unroll
        for (int j4 = 0; j4 < 16; ++j4) { const evf4 w = wr[32 + j4];
            acc[4*j4+0] = fmaf(fv.z, w.x, acc[4*j4+0]);
            acc[4*j4+1] = fmaf(fv.z, w.y, acc[4*j4+1]);
            acc[4*j4+2] = fmaf(fv.z, w.z, acc[4*j4+2]);
            acc[4*j4+3] = fmaf(fv.z, w.w, acc[4*j4+3]); }
#pragma unroll
        for (int j4 = 0; j4 < 16; ++j4) { const evf4 w = wr[48 + j4];
            acc[4*j4+0] = fmaf(fv.w, w.x, acc[4*j4+0]);
            acc[4*j4+1] = fmaf(fv.w, w.y, acc[4*j4+1]);
            acc[4*j4+2] = fmaf(fv.w, w.z, acc[4*j4+2]);
            acc[4*j4+3] = fmaf(fv.w, w.w, acc[4*j4+3]); }
    }
#pragma unroll 1
    for (int q = 0; q < 16; ++q) {
        const float4 fv = fB[q];
        const evf4* wr = reinterpret_cast<const evf4*>(sw1 + (DD + q * 4) * DD);
#pragma unroll
        for (int j4 = 0; j4 < 16; ++j4) { const evf4 w = wr[j4];
            acc[4*j4+0] = fmaf(fv.x, w.x, acc[4*j4+0]);
            acc[4*j4+1] = fmaf(fv.x, w.y, acc[4*j4+1]);
            acc[4*j4+2] = fmaf(fv.x, w.z, acc[4*j4+2]);
            acc[4*j4+3] = fmaf(fv.x, w.w, acc[4*j4+3]); }
#pragma unroll
        for (int j4 = 0; j4 < 16; ++j4) { const evf4 w = wr[16 + j4];
            acc[4*j4+0] = fmaf(fv.y, w.x, acc[4*j4+0]);
            acc[4*j4+1] = fmaf(fv.y, w.y, acc[4*j4+1]);
            acc[4*j4+2] = fmaf(fv.y, w.z, acc[4*j4+2]);
            acc[4*j4+3] = fmaf(fv.y, w.w, acc[4*j4+3]); }
#pragma unroll
        for (int j4 = 0; j4 < 16; ++j4) { const evf4 w = wr[32 + j4];
            acc[4*j4+0] = fmaf(fv.z, w.x, acc[4*j4+0]);
            acc[4*j4+1] = fmaf(fv.z, w.y, acc[4*j4+1]);
            acc[4*j4+2] = fmaf(fv.z, w.z, acc[4*j4+2]);
            acc[4*j4+3] = fmaf(fv.z, w.w, acc[4*j4+3]); }
#pragma unroll
        for (int j4 = 0; j4 < 16; ++j4) { const evf4 w = wr[48 + j4];
            acc[4*j4+0] = fmaf(fv.w, w.x, acc[4*j4+0]);
            acc[4*j4+1] = fmaf(fv.w, w.y, acc[4*j4+1]);
            acc[4*j4+2] = fmaf(fv.w, w.z, acc[4*j4+2]);
            acc[4*j4+3] = fmaf(fv.w, w.w, acc[4*j4+3]); }
    }
    // BN1 + ReLU in place (exact same arithmetic/order as R3-R9)
    {
        const csf g1c = TO_CSF(g1), v1c = TO_CSF(v1), b1c = TO_CSF(b1),
                  m1c = TO_CSF(m1), be1c = TO_CSF(be1);
#pragma unroll
        for (int j = 0; j < DD; ++j) {
            float sc = g1c[j] * (1.0f / sqrtf(v1c[j] + 1e-5f));
            float h  = fmaf(acc[j] + b1c[j] - m1c[j], sc, be1c[j]);
            acc[j] = fmaxf(h, 0.0f);
        }
    }

    // ---- Phase B: fc2 from LDS w2T rows + BN2 + ReLU + fc3 + h2 store ----
    const csf g2c = TO_CSF(g2), v2c = TO_CSF(v2), b2c = TO_CSF(b2),
              m2c = TO_CSF(m2), be2c = TO_CSF(be2), w3c = TO_CSF(w3);
    float s = 0.0f;
    float4* o = reinterpret_cast<float4*>(h2_out) + (size_t)n * 16;
#pragma unroll 1
    for (int jq = 0; jq < 16; ++jq) {
        const evf4* r0 = reinterpret_cast<const evf4*>(sw2 + (4*jq + 0) * DD);
        const evf4* r1 = reinterpret_cast<const evf4*>(sw2 + (4*jq + 1) * DD);
        const evf4* r2 = reinterpret_cast<const evf4*>(sw2 + (4*jq + 2) * DD);
        const evf4* r3 = reinterpret_cast<const evf4*>(sw2 + (4*jq + 3) * DD);
        float a0 = 0.0f, a1 = 0.0f, a2 = 0.0f, a3 = 0.0f;
#pragma unroll
        for (int k4 = 0; k4 < 16; ++k4) {
            const evf4 w0 = r0[k4], w1v = r1[k4], w2v = r2[k4], w3v = r3[k4];
            const float h0 = acc[4*k4+0], h1v = acc[4*k4+1],
                        h2v = acc[4*k4+2], h3v = acc[4*k4+3];
            a0 = fmaf(h0, w0.x, a0); a0 = fmaf(h1v, w0.y, a0);
            a0 = fmaf(h2v, w0.z, a0); a0 = fmaf(h3v, w0.w, a0);
            a1 = fmaf(h0, w1v.x, a1); a1 = fmaf(h1v, w1v.y, a1);
            a1 = fmaf(h2v, w1v.z, a1); a1 = fmaf(h3v, w1v.w, a1);
            a2 = fmaf(h0, w2v.x, a2); a2 = fmaf(h1v, w2v.y, a2);
            a2 = fmaf(h2v, w2v.z, a2); a2 = fmaf(h3v, w2v.w, a2);
            a3 = fmaf(h0, w3v.x, a3); a3 = fmaf(h1v, w3v.y, a3);
            a3 = fmaf(h2v, w3v.z, a3); a3 = fmaf(h3v, w3v.w, a3);
        }
        float hv[4] = {a0, a1, a2, a3};
#pragma unroll
        for (int u = 0; u < 4; ++u) {
            const int jj = 4*jq + u;
            float sc = g2c[jj] * (1.0f / sqrtf(v2c[jj] + 1e-5f));
            float h  = fmaf(hv[u] + b2c[jj] - m2c[jj], sc, be2c[jj]);
            h = fmaxf(h, 0.0f);
            hv[u] = h;
            s = fmaf(h, w3c[jj], s);
        }
        o[jq] = make_float4(hv[0], hv[1], hv[2], hv[3]);
    }
    s += TO_CSF(b3)[0];
    const float score = fmaxf(s, 0.0f);

    // sigmoid(score) > 0.5 via XLA-style logistic expansion (score >= 0)
    const bool on = (0.5f + 0.5f * tanhf(0.5f * score)) > 0.5f;

    // ---- Phase C: geometry + 4 output stores + ballots per plane ----
    const csf4 pp = TO_CSF4(packed);
#pragma unroll 1
    for (int p = 0; p < NP; ++p) {
        const evf4 nrm = pp[p*3+0];
        const evf4 mn  = pp[p*3+1];
        const evf4 mx  = pp[p*3+2];
        float d = fabsf(fmaf(c2, nrm.z, fmaf(c1, nrm.y, c0 * nrm.x)) - nrm.w);
        bool ok0 = (mx.x == 0.0f) | ((c0 >= mn.x) & (c0 < mx.x));
        bool ok1 = (mx.y == 0.0f) | ((c1 >= mn.y) & (c1 < mx.y));
        bool ok2 = (mx.z == 0.0f) | ((c2 >= mn.z) & (c2 < mx.z));
        bool mk  = ok0 & ok1 & ok2 & (d < 0.1f);
        const size_t idx = (size_t)p * NPTS + n;
        const bool mon  = mk & on;
        const bool moff = mk & (!on);
        out_mask[idx] = mk ? 1.0f : 0.0f;
        out_sm[idx]   = mk ? score : 0.0f;
        out_on[idx]   = mon ? 1.0f : 0.0f;
        out_off[idx]  = moff ? 1.0f : 0.0f;
        unsigned long long bOn  = __ballot(mon);
        unsigned long long bOff = __ballot(moff);
        if (lane == 0) {
            hitOn [(size_t)p * NWORDS + word] = bOn;
            hitOff[(size_t)p * NWORDS + word] = bOff;
        }
    }
}

// ---------------------------------------------------------------------------
// Pool, round-14: PLANE-OWNER GATHER (no staging, ~500x fewer atomics).
// R13 post-mortem: dual-chain + 2x TLP on the staged-tile pool netted ~0
// (total 838 vs 832) -> the staged structure is bound by its fixed costs:
// 16.8M atomicMax into 16K addresses (1-2K contenders each), full 64MB h2
// LDS round-trip (98% of rows never hit), 4 blocks/CU TLP cap from the
// 36KB tile. Redesign: block = (plane, side, chunk/16). Scan 256 ballot
// words: each wave loads 64 words coalesced (512B), walks nonzero words
// via __ballot + __shfl (wave-uniform), and per hit does ONE coalesced
// 256B gather h2[n*64+lane] (lane=dim; h2 is L3-hot from fused). ILP-2 on
// the bit loop keeps 2 gathers in flight. LDS = 1KB -> ~8 blocks/CU
// resident, ~32 waves/CU TLP hides gather latency. Final: 4-wave LDS
// reduce + atomicMax per dim (262K atomics total, <=16 contenders per
// address; 0-init by prep + h2>=0 -> exact where(any,max,0) semantics).
// fmax is exactly order-independent -> bit-identical output.
// ---------------------------------------------------------------------------
__global__ __launch_bounds__(256) void pool_kernel(
    const float* __restrict__ h2,
    const unsigned long long* __restrict__ hitOn,
    const unsigned long long* __restrict__ hitOff,
    int* __restrict__ out_feats_i)
{
    __shared__ float sacc[4][DD];
    const int t = threadIdx.x;
    const int lane = t & 63;
    const int wv = t >> 6;

    const int bid   = blockIdx.x;          // 4096 = 128 planes * 2 sides * 16 chunks
    const int p     = bid >> 5;
    const int side  = (bid >> 4) & 1;
    const int chunk = bid & 15;
    const unsigned long long* hsrc = side ? hitOff : hitOn;

    // this wave's 64 words of the plane's ballot bitmap (coalesced 512B)
    const int wbase = chunk * 256 + wv * 64;
    const unsigned long long myw = hsrc[(size_t)p * NWORDS + wbase + lane];

    float acc = 0.0f;
    unsigned long long act = __ballot(myw != 0ULL);
    while (act) {
        const int l = __builtin_ctzll(act);
        act &= act - 1;
        unsigned long long w = __shfl(myw, l, 64);   // wave-uniform word
        const size_t nbase = (size_t)(wbase + l) * 64;
        while (w) {
            const int b0 = __builtin_ctzll(w); w &= w - 1;
            if (w) {
                const int b1 = __builtin_ctzll(w); w &= w - 1;
                const float v0 = h2[(nbase + b0) * DD + lane];
                const float v1 = h2[(nbase + b1) * DD + lane];
                acc = fmaxf(acc, v0);
                acc = fmaxf(acc, v1);
            } else {
                const float v0 = h2[(nbase + b0) * DD + lane];
                acc = fmaxf(acc, v0);
            }
        }
    }

    sacc[wv][lane] = acc;
    __syncthreads();
    if (t < DD) {
        const float m = fmaxf(fmaxf(sacc[0][t], sacc[1][t]),
                              fmaxf(sacc[2][t], sacc[3][t]));
        if (m != 0.0f)
            atomicMax(&out_feats_i[side * NP * DD + p * DD + t], __float_as_int(m));
    }
}

extern "C" void kernel_launch(void* const* d_in, const int* in_sizes, int n_in,
                              void* d_out, int out_size, void* d_ws, size_t ws_size,
                              hipStream_t stream) {
    const float* feature      = (const float*)d_in[0];
    const float* feature_geo  = (const float*)d_in[1];
    const float* xyz          = (const float*)d_in[2];
    const float* centers      = (const float*)d_in[3];
    const float* plane_center = (const float*)d_in[4];
    const float* plane_normal = (const float*)d_in[5];
    const float* pmin         = (const float*)d_in[6];
    const float* pmax         = (const float*)d_in[7];
    const float* w1 = (const float*)d_in[8];
    const float* b1 = (const float*)d_in[9];
    const float* g1 = (const float*)d_in[10];
    const float* be1 = (const float*)d_in[11];
    const float* m1 = (const float*)d_in[12];
    const float* v1 = (const float*)d_in[13];
    const float* w2 = (const float*)d_in[14];
    const float* b2 = (const float*)d_in[15];
    const float* g2 = (const float*)d_in[16];
    const float* be2 = (const float*)d_in[17];
    const float* m2 = (const float*)d_in[18];
    const float* v2 = (const float*)d_in[19];
    const float* w3 = (const float*)d_in[20];
    const float* b3 = (const float*)d_in[21];

    float* out = (float*)d_out;
    const size_t PN = (size_t)NP * NPTS;
    float* out_sm    = out;
    float* out_mask  = out + PN;
    float* out_on    = out + 2 * PN;
    float* out_off   = out + 3 * PN;
    float* out_feats = out + 4 * PN;

    // workspace carve (~73 MB)
    float* h2     = (float*)d_ws;                                // N*64 f32 (64 MB)
    unsigned long long* hitOn  = (unsigned long long*)(h2 + (size_t)NPTS * DD);
    unsigned long long* hitOff = hitOn + (size_t)NP * NWORDS;
    float* packed = (float*)(hitOff + (size_t)NP * NWORDS);      // P*12 f32
    float* w2T    = packed + NP * 12;                            // 64*64 f32

    prep_kernel<<<64, 256, 0, stream>>>(
        plane_center, plane_normal, pmin, pmax, w2, packed, w2T, out_feats);
    fused_kernel<<<NPTS / 256, 256, 0, stream>>>(
        feature, feature_geo, xyz, centers, packed,
        w1, b1, g1, be1, m1, v1, w2T, b2, g2, be2, m2, v2, w3, b3,
        h2, out_sm, out_mask, out_on, out_off, hitOn, hitOff);
    pool_kernel<<<4096, 256, 0, stream>>>(h2, hitOn, hitOff, (int*)out_feats);
}

// Round 6
// 804.215 us; speedup vs baseline: 1.2637x; 1.0247x over previous
//
#include <hip/hip_runtime.h>
#include <hip/hip_bf16.h>
#include <math.h>

// Problem constants (fixed by the reference file)
#define NPTS 262144
#define NP   128
#define DD   64
#define NWORDS (NPTS / 64)   // 4096 u64 ballot words per plane

// AS(4) scalar pointers for small uniform reads (planes/BN). R7 lesson: use
// POD ext_vector for AS(4) vectors (HIP float4 ctors break the host pass).
#define AS4 __attribute__((address_space(4)))
typedef float evf4 __attribute__((ext_vector_type(4)));
typedef AS4 const float* csf;
typedef AS4 const evf4*  csf4;
#define TO_CSF(p)  ((csf)(unsigned long long)(const void*)(p))
#define TO_CSF4(p) ((csf4)(unsigned long long)(const void*)(p))

// ---------------------------------------------------------------------------
// Prep: pack plane params [P][12] (normal.xyz+offs | min.xyz | max.xyz),
// transpose w2 -> w2T[j][k], zero out_feats for the atomic-max pool.
// ---------------------------------------------------------------------------
__global__ __launch_bounds__(256) void prep_kernel(
    const float* __restrict__ plane_center, const float* __restrict__ plane_normal,
    const float* __restrict__ pmin, const float* __restrict__ pmax,
    const float* __restrict__ w2,
    float* __restrict__ packed, float* __restrict__ w2T,
    float* __restrict__ out_feats)
{
    const int t = threadIdx.x;
    out_feats[blockIdx.x * 256 + t] = 0.0f;          // grid = 64 blocks
    if (blockIdx.x == 0 && t < NP) {
        float n0 = plane_normal[t*3+0], n1 = plane_normal[t*3+1], n2 = plane_normal[t*3+2];
        float c0 = plane_center[t*3+0], c1 = plane_center[t*3+1], c2 = plane_center[t*3+2];
        float off = (c0*n0 + c1*n1) + c2*n2;          // matches jnp.sum order
        float4* pp = reinterpret_cast<float4*>(packed) + t * 3;
        pp[0] = make_float4(n0, n1, n2, off);
        pp[1] = make_float4(pmin[t*3+0], pmin[t*3+1], pmin[t*3+2], 0.0f);
        pp[2] = make_float4(pmax[t*3+0], pmax[t*3+1], pmax[t*3+2], 0.0f);
    }
    if (blockIdx.x == 1) {
#pragma unroll
        for (int u = 0; u < 16; ++u) {
            const int e = u * 256 + t;               // e = j*64 + k
            const int j = e >> 6, k = e & 63;
            w2T[e] = w2[k * DD + j];
        }
    }
}

// ---------------------------------------------------------------------------
// Fused per-point kernel, round-15: R9 body + XCD-AWARE BLOCK SWIZZLE.
// R14 post-mortem: controllable budget is fused ~330us (pool ~30, prep ~5,
// fill ~340 + ~120us memsets/gaps fixed by harness). Fused runs at 41% of
// achievable HBM write BW with VALUBusy ~28% -> stall-bound, not pipe-bound.
// Named stall: Phase C writes 256B chunks at p*NPTS+n; adjacent n-windows
// land on DIFFERENT XCDs (hw round-robins blockIdx across 8 XCDs), so each
// XCD L2 holds 1KB fragments strided 8KB and evicts scattered chunks to
// HBM. Fix (T1, bijective; 1024%8==0): n_window = (bid&7)*128 + (bid>>3).
// XCD k then owns a contiguous 32K-point span; per (plane,array) its L2
// sees a contiguous 128KB run with ~all 128 of its blocks co-resident ->
// streaming evictions. Pure locality change: same per-point outputs, same
// ballot words (n>>6 is wave-internal) -> bit-identical, absmax 2.98e-8.
// ---------------------------------------------------------------------------
__global__ __launch_bounds__(256) void fused_kernel(
    const float* __restrict__ feature, const float* __restrict__ feature_geo,
    const float* __restrict__ xyz, const float* __restrict__ centers,
    const float* __restrict__ packed,
    const float* __restrict__ w1, const float* __restrict__ b1,
    const float* __restrict__ g1, const float* __restrict__ be1,
    const float* __restrict__ m1, const float* __restrict__ v1,
    const float* __restrict__ w2T, const float* __restrict__ b2,
    const float* __restrict__ g2, const float* __restrict__ be2,
    const float* __restrict__ m2, const float* __restrict__ v2,
    const float* __restrict__ w3, const float* __restrict__ b3,
    float* __restrict__ h2_out,
    float* __restrict__ out_sm, float* __restrict__ out_mask,
    float* __restrict__ out_on, float* __restrict__ out_off,
    unsigned long long* __restrict__ hitOn, unsigned long long* __restrict__ hitOff)
{
    __shared__ float sw1[128 * DD];   // 32 KB, row-major [k][j] like w1
    __shared__ float sw2[DD * DD];    // 16 KB, w2T layout [j][k]
    const int t = threadIdx.x;
    // XCD-aware bijective swizzle: XCD = bid%8 (hw round-robin); give each
    // XCD a contiguous 128-block (32K-point) span for L2 write locality.
    const int bs = (blockIdx.x & 7) * 128 + (blockIdx.x >> 3);
    const int n = bs * 256 + t;
    const int lane = t & 63;
    const int word = n >> 6;

    // stage weights (coalesced float4; 12 per thread)
    {
        const float4* s1 = reinterpret_cast<const float4*>(w1);
        const float4* s2 = reinterpret_cast<const float4*>(w2T);
        float4* d1 = reinterpret_cast<float4*>(sw1);
        float4* d2 = reinterpret_cast<float4*>(sw2);
#pragma unroll
        for (int k = 0; k < 8; ++k) d1[t + k * 256] = s1[t + k * 256];
#pragma unroll
        for (int k = 0; k < 4; ++k) d2[t + k * 256] = s2[t + k * 256];
    }

    // cloud coords (issue early; used in Phase C)
    const csf cc = TO_CSF(centers);
    const float c0 = xyz[n*3+0] + cc[0];
    const float c1 = xyz[n*3+1] + cc[1];
    const float c2 = xyz[n*3+2] + cc[2];

    __syncthreads();

    float acc[DD];
#pragma unroll
    for (int j = 0; j < DD; ++j) acc[j] = 0.0f;

    // ---- Phase A: fc1 from LDS (q rolled, j-blocks as 16x b128) ----
    const float4* fA = reinterpret_cast<const float4*>(feature) + (size_t)n * 16;
    const float4* fB = reinterpret_cast<const float4*>(feature_geo) + (size_t)n * 16;
#pragma unroll 1
    for (int q = 0; q < 16; ++q) {
        const float4 fv = fA[q];
        const evf4* wr = reinterpret_cast<const evf4*>(sw1 + q * 4 * DD);
#pragma unroll
        for (int j4 = 0; j4 < 16; ++j4) { const evf4 w = wr[j4];
            acc[4*j4+0] = fmaf(fv.x, w.x, acc[4*j4+0]);
            acc[4*j4+1] = fmaf(fv.x, w.y, acc[4*j4+1]);
            acc[4*j4+2] = fmaf(fv.x, w.z, acc[4*j4+2]);
            acc[4*j4+3] = fmaf(fv.x, w.w, acc[4*j4+3]); }
#pragma unroll
        for (int j4 = 0; j4 < 16; ++j4) { const evf4 w = wr[16 + j4];
            acc[4*j4+0] = fmaf(fv.y, w.x, acc[4*j4+0]);
            acc[4*j4+1] = fmaf(fv.y, w.y, acc[4*j4+1]);
            acc[4*j4+2] = fmaf(fv.y, w.z, acc[4*j4+2]);
            acc[4*j4+3] = fmaf(fv.y, w.w, acc[4*j4+3]); }
#pragma unroll
        for (int j4 = 0; j4 < 16; ++j4) { const evf4 w = wr[32 + j4];
            acc[4*j4+0] = fmaf(fv.z, w.x, acc[4*j4+0]);
            acc[4*j4+1] = fmaf(fv.z, w.y, acc[4*j4+1]);
            acc[4*j4+2] = fmaf(fv.z, w.z, acc[4*j4+2]);
            acc[4*j4+3] = fmaf(fv.z, w.w, acc[4*j4+3]); }
#pragma unroll
        for (int j4 = 0; j4 < 16; ++j4) { const evf4 w = wr[48 + j4];
            acc[4*j4+0] = fmaf(fv.w, w.x, acc[4*j4+0]);
            acc[4*j4+1] = fmaf(fv.w, w.y, acc[4*j4+1]);
            acc[4*j4+2] = fmaf(fv.w, w.z, acc[4*j4+2]);
            acc[4*j4+3] = fmaf(fv.w, w.w, acc[4*j4+3]); }
    }
#pragma unroll 1
    for (int q = 0; q < 16; ++q) {
        const float4 fv = fB[q];
        const evf4* wr = reinterpret_cast<const evf4*>(sw1 + (DD + q * 4) * DD);
#pragma unroll
        for (int j4 = 0; j4 < 16; ++j4) { const evf4 w = wr[j4];
            acc[4*j4+0] = fmaf(fv.x, w.x, acc[4*j4+0]);
            acc[4*j4+1] = fmaf(fv.x, w.y, acc[4*j4+1]);
            acc[4*j4+2] = fmaf(fv.x, w.z, acc[4*j4+2]);
            acc[4*j4+3] = fmaf(fv.x, w.w, acc[4*j4+3]); }
#pragma unroll
        for (int j4 = 0; j4 < 16; ++j4) { const evf4 w = wr[16 + j4];
            acc[4*j4+0] = fmaf(fv.y, w.x, acc[4*j4+0]);
            acc[4*j4+1] = fmaf(fv.y, w.y, acc[4*j4+1]);
            acc[4*j4+2] = fmaf(fv.y, w.z, acc[4*j4+2]);
            acc[4*j4+3] = fmaf(fv.y, w.w, acc[4*j4+3]); }
#pragma unroll
        for (int j4 = 0; j4 < 16; ++j4) { const evf4 w = wr[32 + j4];
            acc[4*j4+0] = fmaf(fv.z, w.x, acc[4*j4+0]);
            acc[4*j4+1] = fmaf(fv.z, w.y, acc[4*j4+1]);
            acc[4*j4+2] = fmaf(fv.z, w.z, acc[4*j4+2]);
            acc[4*j4+3] = fmaf(fv.z, w.w, acc[4*j4+3]); }
#pragma unroll
        for (int j4 = 0; j4 < 16; ++j4) { const evf4 w = wr[48 + j4];
            acc[4*j4+0] = fmaf(fv.w, w.x, acc[4*j4+0]);
            acc[4*j4+1] = fmaf(fv.w, w.y, acc[4*j4+1]);
            acc[4*j4+2] = fmaf(fv.w, w.z, acc[4*j4+2]);
            acc[4*j4+3] = fmaf(fv.w, w.w, acc[4*j4+3]); }
    }
    // BN1 + ReLU in place (exact same arithmetic/order as R3-R9)
    {
        const csf g1c = TO_CSF(g1), v1c = TO_CSF(v1), b1c = TO_CSF(b1),
                  m1c = TO_CSF(m1), be1c = TO_CSF(be1);
#pragma unroll
        for (int j = 0; j < DD; ++j) {
            float sc = g1c[j] * (1.0f / sqrtf(v1c[j] + 1e-5f));
            float h  = fmaf(acc[j] + b1c[j] - m1c[j], sc, be1c[j]);
            acc[j] = fmaxf(h, 0.0f);
        }
    }

    // ---- Phase B: fc2 from LDS w2T rows + BN2 + ReLU + fc3 + h2 store ----
    const csf g2c = TO_CSF(g2), v2c = TO_CSF(v2), b2c = TO_CSF(b2),
              m2c = TO_CSF(m2), be2c = TO_CSF(be2), w3c = TO_CSF(w3);
    float s = 0.0f;
    float4* o = reinterpret_cast<float4*>(h2_out) + (size_t)n * 16;
#pragma unroll 1
    for (int jq = 0; jq < 16; ++jq) {
        const evf4* r0 = reinterpret_cast<const evf4*>(sw2 + (4*jq + 0) * DD);
        const evf4* r1 = reinterpret_cast<const evf4*>(sw2 + (4*jq + 1) * DD);
        const evf4* r2 = reinterpret_cast<const evf4*>(sw2 + (4*jq + 2) * DD);
        const evf4* r3 = reinterpret_cast<const evf4*>(sw2 + (4*jq + 3) * DD);
        float a0 = 0.0f, a1 = 0.0f, a2 = 0.0f, a3 = 0.0f;
#pragma unroll
        for (int k4 = 0; k4 < 16; ++k4) {
            const evf4 w0 = r0[k4], w1v = r1[k4], w2v = r2[k4], w3v = r3[k4];
            const float h0 = acc[4*k4+0], h1v = acc[4*k4+1],
                        h2v = acc[4*k4+2], h3v = acc[4*k4+3];
            a0 = fmaf(h0, w0.x, a0); a0 = fmaf(h1v, w0.y, a0);
            a0 = fmaf(h2v, w0.z, a0); a0 = fmaf(h3v, w0.w, a0);
            a1 = fmaf(h0, w1v.x, a1); a1 = fmaf(h1v, w1v.y, a1);
            a1 = fmaf(h2v, w1v.z, a1); a1 = fmaf(h3v, w1v.w, a1);
            a2 = fmaf(h0, w2v.x, a2); a2 = fmaf(h1v, w2v.y, a2);
            a2 = fmaf(h2v, w2v.z, a2); a2 = fmaf(h3v, w2v.w, a2);
            a3 = fmaf(h0, w3v.x, a3); a3 = fmaf(h1v, w3v.y, a3);
            a3 = fmaf(h2v, w3v.z, a3); a3 = fmaf(h3v, w3v.w, a3);
        }
        float hv[4] = {a0, a1, a2, a3};
#pragma unroll
        for (int u = 0; u < 4; ++u) {
            const int jj = 4*jq + u;
            float sc = g2c[jj] * (1.0f / sqrtf(v2c[jj] + 1e-5f));
            float h  = fmaf(hv[u] + b2c[jj] - m2c[jj], sc, be2c[jj]);
            h = fmaxf(h, 0.0f);
            hv[u] = h;
            s = fmaf(h, w3c[jj], s);
        }
        o[jq] = make_float4(hv[0], hv[1], hv[2], hv[3]);
    }
    s += TO_CSF(b3)[0];
    const float score = fmaxf(s, 0.0f);

    // sigmoid(score) > 0.5 via XLA-style logistic expansion (score >= 0)
    const bool on = (0.5f + 0.5f * tanhf(0.5f * score)) > 0.5f;

    // ---- Phase C: geometry + 4 output stores + ballots per plane ----
    const csf4 pp = TO_CSF4(packed);
#pragma unroll 1
    for (int p = 0; p < NP; ++p) {
        const evf4 nrm = pp[p*3+0];
        const evf4 mn  = pp[p*3+1];
        const evf4 mx  = pp[p*3+2];
        float d = fabsf(fmaf(c2, nrm.z, fmaf(c1, nrm.y, c0 * nrm.x)) - nrm.w);
        bool ok0 = (mx.x == 0.0f) | ((c0 >= mn.x) & (c0 < mx.x));
        bool ok1 = (mx.y == 0.0f) | ((c1 >= mn.y) & (c1 < mx.y));
        bool ok2 = (mx.z == 0.0f) | ((c2 >= mn.z) & (c2 < mx.z));
        bool mk  = ok0 & ok1 & ok2 & (d < 0.1f);
        const size_t idx = (size_t)p * NPTS + n;
        const bool mon  = mk & on;
        const bool moff = mk & (!on);
        out_mask[idx] = mk ? 1.0f : 0.0f;
        out_sm[idx]   = mk ? score : 0.0f;
        out_on[idx]   = mon ? 1.0f : 0.0f;
        out_off[idx]  = moff ? 1.0f : 0.0f;
        unsigned long long bOn  = __ballot(mon);
        unsigned long long bOff = __ballot(moff);
        if (lane == 0) {
            hitOn [(size_t)p * NWORDS + word] = bOn;
            hitOff[(size_t)p * NWORDS + word] = bOff;
        }
    }
}

// ---------------------------------------------------------------------------
// Pool, round-14 form (kept): PLANE-OWNER GATHER. Block = (plane, side,
// chunk/16); scan 256 ballot words (coalesced 512B/wave + ballot/shfl walk),
// one coalesced 256B gather h2[n*64+lane] per hit (ILP-2), 4-wave LDS
// reduce, 1 atomicMax per dim (262K atomics, <=16 contenders/address).
// fmax order-independent -> bit-identical. ~30us.
// ---------------------------------------------------------------------------
__global__ __launch_bounds__(256) void pool_kernel(
    const float* __restrict__ h2,
    const unsigned long long* __restrict__ hitOn,
    const unsigned long long* __restrict__ hitOff,
    int* __restrict__ out_feats_i)
{
    __shared__ float sacc[4][DD];
    const int t = threadIdx.x;
    const int lane = t & 63;
    const int wv = t >> 6;

    const int bid   = blockIdx.x;          // 4096 = 128 planes * 2 sides * 16 chunks
    const int p     = bid >> 5;
    const int side  = (bid >> 4) & 1;
    const int chunk = bid & 15;
    const unsigned long long* hsrc = side ? hitOff : hitOn;

    // this wave's 64 words of the plane's ballot bitmap (coalesced 512B)
    const int wbase = chunk * 256 + wv * 64;
    const unsigned long long myw = hsrc[(size_t)p * NWORDS + wbase + lane];

    float acc = 0.0f;
    unsigned long long act = __ballot(myw != 0ULL);
    while (act) {
        const int l = __builtin_ctzll(act);
        act &= act - 1;
        unsigned long long w = __shfl(myw, l, 64);   // wave-uniform word
        const size_t nbase = (size_t)(wbase + l) * 64;
        while (w) {
            const int b0 = __builtin_ctzll(w); w &= w - 1;
            if (w) {
                const int b1 = __builtin_ctzll(w); w &= w - 1;
                const float v0 = h2[(nbase + b0) * DD + lane];
                const float v1 = h2[(nbase + b1) * DD + lane];
                acc = fmaxf(acc, v0);
                acc = fmaxf(acc, v1);
            } else {
                const float v0 = h2[(nbase + b0) * DD + lane];
                acc = fmaxf(acc, v0);
            }
        }
    }

    sacc[wv][lane] = acc;
    __syncthreads();
    if (t < DD) {
        const float m = fmaxf(fmaxf(sacc[0][t], sacc[1][t]),
                              fmaxf(sacc[2][t], sacc[3][t]));
        if (m != 0.0f)
            atomicMax(&out_feats_i[side * NP * DD + p * DD + t], __float_as_int(m));
    }
}

extern "C" void kernel_launch(void* const* d_in, const int* in_sizes, int n_in,
                              void* d_out, int out_size, void* d_ws, size_t ws_size,
                              hipStream_t stream) {
    const float* feature      = (const float*)d_in[0];
    const float* feature_geo  = (const float*)d_in[1];
    const float* xyz          = (const float*)d_in[2];
    const float* centers      = (const float*)d_in[3];
    const float* plane_center = (const float*)d_in[4];
    const float* plane_normal = (const float*)d_in[5];
    const float* pmin         = (const float*)d_in[6];
    const float* pmax         = (const float*)d_in[7];
    const float* w1 = (const float*)d_in[8];
    const float* b1 = (const float*)d_in[9];
    const float* g1 = (const float*)d_in[10];
    const float* be1 = (const float*)d_in[11];
    const float* m1 = (const float*)d_in[12];
    const float* v1 = (const float*)d_in[13];
    const float* w2 = (const float*)d_in[14];
    const float* b2 = (const float*)d_in[15];
    const float* g2 = (const float*)d_in[16];
    const float* be2 = (const float*)d_in[17];
    const float* m2 = (const float*)d_in[18];
    const float* v2 = (const float*)d_in[19];
    const float* w3 = (const float*)d_in[20];
    const float* b3 = (const float*)d_in[21];

    float* out = (float*)d_out;
    const size_t PN = (size_t)NP * NPTS;
    float* out_sm    = out;
    float* out_mask  = out + PN;
    float* out_on    = out + 2 * PN;
    float* out_off   = out + 3 * PN;
    float* out_feats = out + 4 * PN;

    // workspace carve (~73 MB)
    float* h2     = (float*)d_ws;                                // N*64 f32 (64 MB)
    unsigned long long* hitOn  = (unsigned long long*)(h2 + (size_t)NPTS * DD);
    unsigned long long* hitOff = hitOn + (size_t)NP * NWORDS;
    float* packed = (float*)(hitOff + (size_t)NP * NWORDS);      // P*12 f32
    float* w2T    = packed + NP * 12;                            // 64*64 f32

    prep_kernel<<<64, 256, 0, stream>>>(
        plane_center, plane_normal, pmin, pmax, w2, packed, w2T, out_feats);
    fused_kernel<<<NPTS / 256, 256, 0, stream>>>(
        feature, feature_geo, xyz, centers, packed,
        w1, b1, g1, be1, m1, v1, w2T, b2, g2, be2, m2, v2, w3, b3,
        h2, out_sm, out_mask, out_on, out_off, hitOn, hitOff);
    pool_kernel<<<4096, 256, 0, stream>>>(h2, hitOn, hitOff, (int*)out_feats);
}